// Round 1
// baseline (1258.505 us; speedup 1.0000x reference)
//
#include <hip/hip_runtime.h>
#include <math.h>

// SymNet fused model, fp32 correctness-first implementation.
// Structure exploits L=1: mamba block reduces to
//   u = rmsnorm(h); xz = u@Wi; x = silu(x*cw[:,3]+cb); xdbl = x@Wx;
//   dt = softplus(xdbl[:,:32]@Wdt + bdt); bc = dot(xdbl[32:48], xdbl[48:64]);
//   y = x*(dt*bc + D); h += (y*silu(z)) @ Wo

__device__ __forceinline__ float siluf(float v){ return v / (1.f + __expf(-v)); }
__device__ __forceinline__ float softplusf(float v){ return v > 20.f ? v : log1pf(__expf(v)); }

// ---------------- frontend: conv2d + enc + proj → h (B,512) ----------------
__global__ __launch_bounds__(256) void k_frontend(
    const float* __restrict__ obs, const float* __restrict__ comm_in,
    const float* __restrict__ conv_w, const float* __restrict__ conv_b,
    const float* __restrict__ enc_w, const float* __restrict__ enc_b,
    const float* __restrict__ proj_w, const float* __restrict__ proj_b,
    float* __restrict__ h)
{
  __shared__ float s_obs[8][76];
  __shared__ float s_v[8][288];
  __shared__ float s_cat[8][384];
  const int t = threadIdx.x;
  const int r0 = blockIdx.x * 8;

  for (int i = t; i < 8*75; i += 256) s_obs[i/75][i%75] = obs[(size_t)(r0 + i/75)*75 + i%75];
  __syncthreads();

  // conv 3x5x5 -> 32x3x3 (VALID), relu
  for (int i = t; i < 8*288; i += 256) {
    int r = i / 288, o = i % 288;
    int c = o / 9, ij = o % 9, oi = ij/3, oj = ij%3;
    float acc = conv_b[c];
    #pragma unroll
    for (int ic=0; ic<3; ic++)
      #pragma unroll
      for (int ki=0; ki<3; ki++)
        #pragma unroll
        for (int kj=0; kj<3; kj++)
          acc = fmaf(s_obs[r][ic*25 + (oi+ki)*5 + (oj+kj)], conv_w[((c*3+ic)*3+ki)*3+kj], acc);
    s_v[r][o] = fmaxf(acc, 0.f);
  }
  __syncthreads();

  { // emb = relu(v @ enc_w + enc_b): thread t owns column t
    float acc[8];
    #pragma unroll
    for (int r=0;r<8;r++) acc[r] = enc_b[t];
    for (int k=0;k<288;k++) {
      float w = enc_w[k*256 + t];
      #pragma unroll
      for (int r=0;r<8;r++) acc[r] = fmaf(s_v[r][k], w, acc[r]);
    }
    #pragma unroll
    for (int r=0;r<8;r++) s_cat[r][t] = fmaxf(acc[r], 0.f);
  }
  for (int i = t; i < 8*128; i += 256) s_cat[i/128][256 + i%128] = comm_in[(size_t)(r0 + i/128)*128 + i%128];
  __syncthreads();

  { // x = relu(cat @ proj_w + proj_b): thread t owns columns t, t+256
    float a0[8], a1[8];
    #pragma unroll
    for (int r=0;r<8;r++){ a0[r]=proj_b[t]; a1[r]=proj_b[t+256]; }
    for (int k=0;k<384;k++) {
      float w0 = proj_w[k*512 + t];
      float w1 = proj_w[k*512 + t + 256];
      #pragma unroll
      for (int r=0;r<8;r++){ float v = s_cat[r][k]; a0[r]=fmaf(v,w0,a0[r]); a1[r]=fmaf(v,w1,a1[r]); }
    }
    #pragma unroll
    for (int r=0;r<8;r++){
      h[(size_t)(r0+r)*512 + t]       = fmaxf(a0[r], 0.f);
      h[(size_t)(r0+r)*512 + t + 256] = fmaxf(a1[r], 0.f);
    }
  }
}

// ---------------- per layer: rmsnorm + in_proj GEMM + conv1d-collapse + silu ----------------
// xs = silu(xz[:, :1024]*cw3 + cb), zs = silu(xz[:, 1024:])
__global__ __launch_bounds__(256) void k_inproj(
    const float* __restrict__ h, const float* __restrict__ norm_w,
    const float* __restrict__ Wi, const float* __restrict__ cw,
    const float* __restrict__ cb, float* __restrict__ xs, float* __restrict__ zs)
{
  __shared__ float s_u[8][512];
  const int t = threadIdx.x;
  const int r0 = blockIdx.x * 8;
  const int r = t >> 5, lane = t & 31;

  // load + rmsnorm (32 lanes per row, butterfly reduce within 32-lane groups)
  float ss = 0.f;
  for (int k = lane; k < 512; k += 32) { float v = h[(size_t)(r0+r)*512 + k]; s_u[r][k] = v; ss = fmaf(v,v,ss); }
  #pragma unroll
  for (int m=16;m;m>>=1) ss += __shfl_xor(ss, m, 64);
  float rms = rsqrtf(ss * (1.f/512.f) + 1e-5f);
  for (int k = lane; k < 512; k += 32) s_u[r][k] *= rms * norm_w[k];
  __syncthreads();

  // GEMM: 8 rows x 2048 cols; thread t owns cols [4t..4t+3] and [1024+4t..1024+4t+3]
  float acc[8][8];
  #pragma unroll
  for (int a=0;a<8;a++)
    #pragma unroll
    for (int b=0;b<8;b++) acc[a][b]=0.f;

  const float* Wp0 = Wi + 4*t;
  const float* Wp1 = Wi + 1024 + 4*t;
  for (int k=0;k<512;k+=4) {
    float4 u4[8];
    #pragma unroll
    for (int r2=0;r2<8;r2++) u4[r2] = *(const float4*)&s_u[r2][k];
    #pragma unroll
    for (int kk=0;kk<4;kk++) {
      float4 w0 = *(const float4*)(Wp0 + (size_t)(k+kk)*2048);
      float4 w1 = *(const float4*)(Wp1 + (size_t)(k+kk)*2048);
      #pragma unroll
      for (int r2=0;r2<8;r2++) {
        float uv = ((const float*)&u4[r2])[kk];
        acc[r2][0]=fmaf(uv,w0.x,acc[r2][0]); acc[r2][1]=fmaf(uv,w0.y,acc[r2][1]);
        acc[r2][2]=fmaf(uv,w0.z,acc[r2][2]); acc[r2][3]=fmaf(uv,w0.w,acc[r2][3]);
        acc[r2][4]=fmaf(uv,w1.x,acc[r2][4]); acc[r2][5]=fmaf(uv,w1.y,acc[r2][5]);
        acc[r2][6]=fmaf(uv,w1.z,acc[r2][6]); acc[r2][7]=fmaf(uv,w1.w,acc[r2][7]);
      }
    }
  }

  float cwv[4], cbv[4];
  #pragma unroll
  for (int m=0;m<4;m++){ cwv[m] = cw[(4*t+m)*4 + 3]; cbv[m] = cb[4*t+m]; }
  #pragma unroll
  for (int r2=0;r2<8;r2++) {
    float4 xo, zo;
    float* xp = (float*)&xo; float* zp = (float*)&zo;
    #pragma unroll
    for (int m=0;m<4;m++) {
      xp[m] = siluf(fmaf(acc[r2][m], cwv[m], cbv[m]));
      zp[m] = siluf(acc[r2][4+m]);
    }
    *(float4*)&xs[(size_t)(r0+r2)*1024 + 4*t] = xo;
    *(float4*)&zs[(size_t)(r0+r2)*1024 + 4*t] = zo;
  }
}

// ---------------- per layer: x_proj, dt_proj, scalar SSM (L=1), gate -> g (into xs) ----------------
__global__ __launch_bounds__(256) void k_ssm(
    float* __restrict__ xs, const float* __restrict__ zs,
    const float* __restrict__ Wx, const float* __restrict__ Wdt,
    const float* __restrict__ bdt, const float* __restrict__ Dp)
{
  __shared__ float s_x[8][1024];
  __shared__ float s_dbl[8][64];
  __shared__ float s_bc[8];
  const int t = threadIdx.x;
  const int r0 = blockIdx.x * 8;

  {
    const float4* xin = (const float4*)(xs + (size_t)r0*1024);
    float4* s4 = (float4*)&s_x[0][0];
    for (int i=t;i<2048;i+=256) s4[i] = xin[i];
  }
  __syncthreads();

  // x_dbl = xs @ Wx (1024 -> 64)
  for (int i=t;i<512;i+=256) {
    int rr = i >> 6, j = i & 63;
    float acc = 0.f;
    for (int k=0;k<1024;k++) acc = fmaf(s_x[rr][k], Wx[(size_t)k*64 + j], acc);
    s_dbl[rr][j] = acc;
  }
  __syncthreads();
  if (t < 8) {
    float acc=0.f;
    #pragma unroll
    for (int s=0;s<16;s++) acc = fmaf(s_dbl[t][32+s], s_dbl[t][48+s], acc);
    s_bc[t] = acc;
  }
  __syncthreads();

  // dt = softplus(xdbl[:, :32] @ Wdt + bdt); y = x*(dt*bc + D); g = y*silu_z
  for (int c=0;c<4;c++) {
    int j = t + c*256;
    float w[32];
    #pragma unroll
    for (int k=0;k<32;k++) w[k] = Wdt[(size_t)k*1024 + j];
    float bj = bdt[j], dpj = Dp[j];
    for (int rr=0;rr<8;rr++) {
      float acc = bj;
      #pragma unroll
      for (int k=0;k<32;k++) acc = fmaf(s_dbl[rr][k], w[k], acc);
      float dtv = softplusf(acc);
      float yv = s_x[rr][j] * fmaf(dtv, s_bc[rr], dpj);
      xs[(size_t)(r0+rr)*1024 + j] = yv * zs[(size_t)(r0+rr)*1024 + j];
    }
  }
}

// ---------------- per layer: h += g @ Wo (1024 -> 512) ----------------
__global__ __launch_bounds__(256) void k_outproj(
    const float* __restrict__ g, const float* __restrict__ Wo, float* __restrict__ h)
{
  __shared__ float s_g[16][512];
  const int t = threadIdx.x;
  const int r0 = blockIdx.x * 16;
  float acc0[16], acc1[16];
  #pragma unroll
  for (int r=0;r<16;r++){acc0[r]=0.f;acc1[r]=0.f;}

  for (int kc=0;kc<2;kc++) {
    {
      const float4* g4 = (const float4*)g;
      float4* s4 = (float4*)&s_g[0][0];
      for (int i=t;i<2048;i+=256) {
        int row = i >> 7, c4 = i & 127;
        s4[i] = g4[(size_t)(r0+row)*256 + kc*128 + c4];
      }
    }
    __syncthreads();
    for (int k=0;k<512;k+=4) {
      float4 gg[16];
      #pragma unroll
      for (int r=0;r<16;r++) gg[r] = *(const float4*)&s_g[r][k];
      #pragma unroll
      for (int kk=0;kk<4;kk++) {
        float w0 = Wo[(size_t)(kc*512+k+kk)*512 + t];
        float w1 = Wo[(size_t)(kc*512+k+kk)*512 + t + 256];
        #pragma unroll
        for (int r=0;r<16;r++) {
          float gv = ((const float*)&gg[r])[kk];
          acc0[r]=fmaf(gv,w0,acc0[r]); acc1[r]=fmaf(gv,w1,acc1[r]);
        }
      }
    }
    __syncthreads();
  }
  #pragma unroll
  for (int r=0;r<16;r++){
    h[(size_t)(r0+r)*512 + t]       += acc0[r];
    h[(size_t)(r0+r)*512 + t + 256] += acc1[r];
  }
}

// ---------------- final rmsnorm + 3 heads ----------------
__global__ __launch_bounds__(256) void k_heads(
    const float* __restrict__ h, const float* __restrict__ fnw,
    const float* __restrict__ act_w, const float* __restrict__ act_b,
    const float* __restrict__ comm_w, const float* __restrict__ comm_b,
    const float* __restrict__ val_w, const float* __restrict__ val_b,
    float* __restrict__ out)
{
  __shared__ float s_h[8][512];
  const int t = threadIdx.x;
  const int r0 = blockIdx.x * 8;
  const int r = t >> 5, lane = t & 31;
  float ss = 0.f;
  for (int k=lane;k<512;k+=32){ float v = h[(size_t)(r0+r)*512+k]; s_h[r][k]=v; ss=fmaf(v,v,ss); }
  #pragma unroll
  for (int m=16;m;m>>=1) ss += __shfl_xor(ss, m, 64);
  float rms = rsqrtf(ss*(1.f/512.f) + 1e-5f);
  for (int k=lane;k<512;k+=32) s_h[r][k] *= rms * fnw[k];
  __syncthreads();

  for (int i=t;i<8*133;i+=256) {
    int rr = i/133, o = i%133;
    if (o < 4) {
      float acc = act_b[o];
      for (int k=0;k<512;k++) acc = fmaf(s_h[rr][k], act_w[k*4+o], acc);
      out[(size_t)(r0+rr)*4 + o] = acc;
    } else if (o < 132) {
      int j = o-4;
      float acc = comm_b[j];
      for (int k=0;k<512;k++) acc = fmaf(s_h[rr][k], comm_w[k*128+j], acc);
      out[32768 + (size_t)(r0+rr)*128 + j] = tanhf(acc);
    } else {
      float acc = val_b[0];
      for (int k=0;k<512;k++) acc = fmaf(s_h[rr][k], val_w[k], acc);
      out[1081344 + (size_t)(r0+rr)] = acc;
    }
  }
}

extern "C" void kernel_launch(void* const* d_in, const int* in_sizes, int n_in,
                              void* d_out, int out_size, void* d_ws, size_t ws_size,
                              hipStream_t stream) {
  const float* obs       = (const float*)d_in[0];
  const float* comm_in   = (const float*)d_in[1];
  const float* conv_w    = (const float*)d_in[2];
  const float* conv_b    = (const float*)d_in[3];
  const float* enc_w     = (const float*)d_in[4];
  const float* enc_b     = (const float*)d_in[5];
  const float* proj_w    = (const float*)d_in[6];
  const float* proj_b    = (const float*)d_in[7];
  const float* norm_w    = (const float*)d_in[8];
  const float* in_proj_w = (const float*)d_in[9];
  const float* conv1d_w  = (const float*)d_in[10];
  const float* conv1d_b  = (const float*)d_in[11];
  const float* x_proj_w  = (const float*)d_in[12];
  const float* dt_proj_w = (const float*)d_in[13];
  const float* dt_proj_b = (const float*)d_in[14];
  // d_in[15] = A_log: dead code at L=1 (dA multiplies h0 == 0)
  const float* D_param   = (const float*)d_in[16];
  const float* out_proj_w= (const float*)d_in[17];
  const float* final_nw  = (const float*)d_in[18];
  const float* act_w     = (const float*)d_in[19];
  const float* act_b     = (const float*)d_in[20];
  const float* comm_w    = (const float*)d_in[21];
  const float* comm_b    = (const float*)d_in[22];
  const float* val_w     = (const float*)d_in[23];
  const float* val_b     = (const float*)d_in[24];
  float* out = (float*)d_out;

  float* ws = (float*)d_ws;
  float* h  = ws;                       // 8192*512  floats (16 MB)
  float* xs = h  + (size_t)8192*512;    // 8192*1024 floats (32 MB), reused for g
  float* zs = xs + (size_t)8192*1024;   // 8192*1024 floats (32 MB)

  k_frontend<<<1024,256,0,stream>>>(obs, comm_in, conv_w, conv_b, enc_w, enc_b, proj_w, proj_b, h);
  for (int L=0; L<2; L++) {
    k_inproj<<<1024,256,0,stream>>>(h, norm_w + L*512, in_proj_w + (size_t)L*512*2048,
                                    conv1d_w + L*1024*4, conv1d_b + L*1024, xs, zs);
    k_ssm<<<1024,256,0,stream>>>(xs, zs, x_proj_w + (size_t)L*1024*64,
                                 dt_proj_w + (size_t)L*32*1024, dt_proj_b + L*1024,
                                 D_param + L*1024);
    k_outproj<<<512,256,0,stream>>>(xs, out_proj_w + (size_t)L*1024*512, h);
  }
  k_heads<<<1024,256,0,stream>>>(h, final_nw, act_w, act_b, comm_w, comm_b, val_w, val_b, out);
}

// Round 2
// 572.965 us; speedup vs baseline: 2.1965x; 2.1965x over previous
//
#include <hip/hip_runtime.h>
#include <math.h>

// SymNet fused model. L=1 collapses the mamba block to:
//   u = rmsnorm(h); xz = u@Wi; x = silu(xz[:,:1024]*cw[:,3]+cb); z' = silu(xz[:,1024:])
//   xdbl = x@Wx; dt = softplus(xdbl[:,:32]@Wdt + bdt); bc = dot(xdbl[:,32:48], xdbl[:,48:64])
//   g = x*(dt*bc + D) * z'; h += g@Wo
// A_log (dA) is dead code: dA multiplies h0 == 0.
// R2: in_proj/out_proj GEMMs on bf16 MFMA (m97 structure: 128x128 tile, BK=64,
// global_load_lds x16, B^T operand from per-launch transpose-convert).

typedef __bf16 bf16x8 __attribute__((ext_vector_type(8)));
typedef float f32x4 __attribute__((ext_vector_type(4)));
typedef short short8 __attribute__((ext_vector_type(8)));

__device__ __forceinline__ float siluf(float v){ return v / (1.f + __expf(-v)); }
__device__ __forceinline__ float softplusf(float v){ return v > 20.f ? v : log1pf(__expf(v)); }
__device__ __forceinline__ float b2f(unsigned short u){ return __uint_as_float(((unsigned)u)<<16); }
__device__ __forceinline__ unsigned short f2b(float f){
  unsigned u = __float_as_uint(f);
  return (unsigned short)((u + 0x7fffu + ((u>>16)&1u)) >> 16);
}
__device__ __forceinline__ void g2l16(const void* g, void* l){
  __builtin_amdgcn_global_load_lds((const __attribute__((address_space(1))) unsigned int*)g,
                                   (__attribute__((address_space(3))) unsigned int*)l, 16, 0, 0);
}

// ---------------- weight transpose-convert: W fp32 [Kd][Nd] -> Wt bf16 [Nd][Kd] ----------------
__global__ __launch_bounds__(256) void k_wt(const float* __restrict__ W,
                                            unsigned short* __restrict__ Wt, int Kd, int Nd)
{
  __shared__ float s[32][33];
  const int kb = blockIdx.x*32, nb = blockIdx.y*32;
  const int c = threadIdx.x & 31, r = threadIdx.x >> 5;   // r = 0..7
  #pragma unroll
  for (int i=0;i<32;i+=8) s[r+i][c] = W[(size_t)(kb+r+i)*Nd + nb + c];
  __syncthreads();
  #pragma unroll
  for (int i=0;i<32;i+=8) Wt[(size_t)(nb+r+i)*Kd + kb + c] = f2b(s[c][r+i]);
}

// ---------------- rmsnorm -> bf16 (one row per wave) ----------------
__global__ __launch_bounds__(256) void k_rms(const float* __restrict__ h,
                                             const float* __restrict__ nw,
                                             unsigned short* __restrict__ u)
{
  const int l = threadIdx.x & 63;
  const size_t row = (size_t)blockIdx.x*4 + (threadIdx.x>>6);
  const float4* hp = (const float4*)(h + row*512) + l*2;
  float4 v0 = hp[0], v1 = hp[1];
  float ss = v0.x*v0.x+v0.y*v0.y+v0.z*v0.z+v0.w*v0.w
           + v1.x*v1.x+v1.y*v1.y+v1.z*v1.z+v1.w*v1.w;
  #pragma unroll
  for (int m=32;m;m>>=1) ss += __shfl_xor(ss, m, 64);
  const float sc = rsqrtf(ss*(1.f/512.f) + 1e-5f);
  const float4* np = (const float4*)nw + l*2;
  float4 w0 = np[0], w1 = np[1];
  short8 o;
  o[0]=(short)f2b(v0.x*sc*w0.x); o[1]=(short)f2b(v0.y*sc*w0.y);
  o[2]=(short)f2b(v0.z*sc*w0.z); o[3]=(short)f2b(v0.w*sc*w0.w);
  o[4]=(short)f2b(v1.x*sc*w1.x); o[5]=(short)f2b(v1.y*sc*w1.y);
  o[6]=(short)f2b(v1.z*sc*w1.z); o[7]=(short)f2b(v1.w*sc*w1.w);
  *(short8*)(u + row*512 + l*8) = o;
}

// ---------------- MFMA 128x128 tile mainloop (A [M][K] bf16, Bt [N][K] bf16) ----------------
template<int K>
__device__ __forceinline__ void gemm128(const unsigned short* __restrict__ A,
                                        const unsigned short* __restrict__ Bt,
                                        int r0, int c0,
                                        unsigned short* sA, unsigned short* sB,
                                        f32x4 acc[4][4])
{
  const int tid = threadIdx.x;
  const int l = tid & 63;
  const int wr = (tid>>7)&1, wc = (tid>>6)&1;
  const int rowA = tid>>3, kc8 = (tid&7)*8;
  const unsigned short* gA = A  + (size_t)(r0+rowA)*K + kc8;
  const unsigned short* gB = Bt + (size_t)(c0+rowA)*K + kc8;
  const int aOff = (wr*64 + (l&15))*64 + ((l>>4)*8);
  const int bOff = (wc*64 + (l&15))*64 + ((l>>4)*8);
  for (int kt=0; kt<K; kt+=64) {
    #pragma unroll
    for (int it=0; it<4; ++it) {
      g2l16(gA + (size_t)(it*32)*K + kt, sA + ((it*256+tid)*8));
      g2l16(gB + (size_t)(it*32)*K + kt, sB + ((it*256+tid)*8));
    }
    __syncthreads();
    #pragma unroll
    for (int ks=0; ks<64; ks+=32) {
      bf16x8 af[4], bfm[4];
      #pragma unroll
      for (int m=0;m<4;m++) af[m]  = *(const bf16x8*)(sA + (m*16)*64 + aOff + ks);
      #pragma unroll
      for (int n=0;n<4;n++) bfm[n] = *(const bf16x8*)(sB + (n*16)*64 + bOff + ks);
      #pragma unroll
      for (int m=0;m<4;m++)
        #pragma unroll
        for (int n=0;n<4;n++)
          acc[m][n] = __builtin_amdgcn_mfma_f32_16x16x32_bf16(af[m], bfm[n], acc[m][n], 0, 0, 0);
    }
    __syncthreads();
  }
}

// ---------------- in_proj: u_b(8192x512) @ Wi -> silu/conv-collapse -> xs,zs bf16 ----------------
__global__ __launch_bounds__(256) void k_gemm_inproj(
    const unsigned short* __restrict__ A, const unsigned short* __restrict__ Bt,
    const float* __restrict__ cw, const float* __restrict__ cb,
    unsigned short* __restrict__ xs, unsigned short* __restrict__ zs)
{
  __shared__ unsigned short sA[128*64], sB[128*64];
  f32x4 acc[4][4];
  #pragma unroll
  for (int m=0;m<4;m++)
    #pragma unroll
    for (int n=0;n<4;n++) acc[m][n] = (f32x4){0.f,0.f,0.f,0.f};
  const int r0 = blockIdx.x*128, c0 = blockIdx.y*128;
  gemm128<512>(A, Bt, r0, c0, sA, sB, acc);

  const int tid = threadIdx.x, l = tid & 63;
  const int wr = (tid>>7)&1, wc = (tid>>6)&1;
  const int colB = c0 + wc*64 + (l&15);
  const int rowB = r0 + wr*64 + ((l>>4)*4);
  if (c0 < 1024) {
    #pragma unroll
    for (int n=0;n<4;n++){
      const int col = colB + n*16;
      const float cw3 = cw[col*4+3], cbv = cb[col];
      #pragma unroll
      for (int m=0;m<4;m++)
        #pragma unroll
        for (int j=0;j<4;j++){
          const int row = rowB + m*16 + j;
          xs[(size_t)row*1024 + col] = f2b(siluf(fmaf(acc[m][n][j], cw3, cbv)));
        }
    }
  } else {
    #pragma unroll
    for (int n=0;n<4;n++){
      const int col = colB + n*16 - 1024;
      #pragma unroll
      for (int m=0;m<4;m++)
        #pragma unroll
        for (int j=0;j<4;j++){
          const int row = rowB + m*16 + j;
          zs[(size_t)row*1024 + col] = f2b(siluf(acc[m][n][j]));
        }
    }
  }
}

// ---------------- out_proj: g(8192x1024) @ Wo -> h += ----------------
__global__ __launch_bounds__(256) void k_gemm_outproj(
    const unsigned short* __restrict__ A, const unsigned short* __restrict__ Bt,
    float* __restrict__ h)
{
  __shared__ unsigned short sA[128*64], sB[128*64];
  f32x4 acc[4][4];
  #pragma unroll
  for (int m=0;m<4;m++)
    #pragma unroll
    for (int n=0;n<4;n++) acc[m][n] = (f32x4){0.f,0.f,0.f,0.f};
  const int r0 = blockIdx.x*128, c0 = blockIdx.y*128;
  gemm128<1024>(A, Bt, r0, c0, sA, sB, acc);

  const int tid = threadIdx.x, l = tid & 63;
  const int wr = (tid>>7)&1, wc = (tid>>6)&1;
  const int colB = c0 + wc*64 + (l&15);
  const int rowB = r0 + wr*64 + ((l>>4)*4);
  #pragma unroll
  for (int n=0;n<4;n++){
    const int col = colB + n*16;
    #pragma unroll
    for (int m=0;m<4;m++)
      #pragma unroll
      for (int j=0;j<4;j++){
        const int row = rowB + m*16 + j;
        h[(size_t)row*512 + col] += acc[m][n][j];
      }
  }
}

// ---------------- frontend: conv2d + enc + proj -> h (B,512) fp32 ----------------
__global__ __launch_bounds__(256) void k_frontend(
    const float* __restrict__ obs, const float* __restrict__ comm_in,
    const float* __restrict__ conv_w, const float* __restrict__ conv_b,
    const float* __restrict__ enc_w, const float* __restrict__ enc_b,
    const float* __restrict__ proj_w, const float* __restrict__ proj_b,
    float* __restrict__ h)
{
  __shared__ float s_obs[8][76];
  __shared__ float s_v[8][288];
  __shared__ float s_cat[8][384];
  const int t = threadIdx.x;
  const int r0 = blockIdx.x * 8;

  for (int i = t; i < 8*75; i += 256) s_obs[i/75][i%75] = obs[(size_t)(r0 + i/75)*75 + i%75];
  __syncthreads();

  for (int i = t; i < 8*288; i += 256) {
    int r = i / 288, o = i % 288;
    int c = o / 9, ij = o % 9, oi = ij/3, oj = ij%3;
    float acc = conv_b[c];
    #pragma unroll
    for (int ic=0; ic<3; ic++)
      #pragma unroll
      for (int ki=0; ki<3; ki++)
        #pragma unroll
        for (int kj=0; kj<3; kj++)
          acc = fmaf(s_obs[r][ic*25 + (oi+ki)*5 + (oj+kj)], conv_w[((c*3+ic)*3+ki)*3+kj], acc);
    s_v[r][o] = fmaxf(acc, 0.f);
  }
  __syncthreads();

  {
    float acc[8];
    #pragma unroll
    for (int r=0;r<8;r++) acc[r] = enc_b[t];
    for (int k=0;k<288;k++) {
      float w = enc_w[k*256 + t];
      #pragma unroll
      for (int r=0;r<8;r++) acc[r] = fmaf(s_v[r][k], w, acc[r]);
    }
    #pragma unroll
    for (int r=0;r<8;r++) s_cat[r][t] = fmaxf(acc[r], 0.f);
  }
  for (int i = t; i < 8*128; i += 256) s_cat[i/128][256 + i%128] = comm_in[(size_t)(r0 + i/128)*128 + i%128];
  __syncthreads();

  {
    float a0[8], a1[8];
    #pragma unroll
    for (int r=0;r<8;r++){ a0[r]=proj_b[t]; a1[r]=proj_b[t+256]; }
    for (int k=0;k<384;k++) {
      float w0 = proj_w[k*512 + t];
      float w1 = proj_w[k*512 + t + 256];
      #pragma unroll
      for (int r=0;r<8;r++){ float v = s_cat[r][k]; a0[r]=fmaf(v,w0,a0[r]); a1[r]=fmaf(v,w1,a1[r]); }
    }
    #pragma unroll
    for (int r=0;r<8;r++){
      h[(size_t)(r0+r)*512 + t]       = fmaxf(a0[r], 0.f);
      h[(size_t)(r0+r)*512 + t + 256] = fmaxf(a1[r], 0.f);
    }
  }
}

// ---------------- SSM middle: x_proj, dt_proj, L=1 scan, gate -> g (bf16, in place of xs) ----------------
__global__ __launch_bounds__(256) void k_ssm(
    unsigned short* __restrict__ xs, const unsigned short* __restrict__ zs,
    const float* __restrict__ Wx, const float* __restrict__ Wdt,
    const float* __restrict__ bdt, const float* __restrict__ Dp)
{
  __shared__ float s_x[8][1024];
  __shared__ float s_dbl[8][64];
  __shared__ float s_bc[8];
  const int t = threadIdx.x;
  const int r0 = blockIdx.x * 8;

  for (int i=t; i<1024; i+=256) {
    short8 v = *(const short8*)(xs + (size_t)r0*1024 + i*8);
    float* d = &s_x[0][0] + i*8;
    #pragma unroll
    for (int j=0;j<8;j++) d[j] = b2f((unsigned short)v[j]);
  }
  __syncthreads();

  for (int i=t;i<512;i+=256) {
    int rr = i >> 6, j = i & 63;
    float acc = 0.f;
    for (int k=0;k<1024;k++) acc = fmaf(s_x[rr][k], Wx[(size_t)k*64 + j], acc);
    s_dbl[rr][j] = acc;
  }
  __syncthreads();
  if (t < 8) {
    float acc=0.f;
    #pragma unroll
    for (int s=0;s<16;s++) acc = fmaf(s_dbl[t][32+s], s_dbl[t][48+s], acc);
    s_bc[t] = acc;
  }
  __syncthreads();

  for (int c=0;c<4;c++) {
    int j = t + c*256;
    float w[32];
    #pragma unroll
    for (int k=0;k<32;k++) w[k] = Wdt[(size_t)k*1024 + j];
    float bj = bdt[j], dpj = Dp[j];
    for (int rr=0;rr<8;rr++) {
      float acc = bj;
      #pragma unroll
      for (int k=0;k<32;k++) acc = fmaf(s_dbl[rr][k], w[k], acc);
      float dtv = softplusf(acc);
      float yv = s_x[rr][j] * fmaf(dtv, s_bc[rr], dpj);
      float zv = b2f(zs[(size_t)(r0+rr)*1024 + j]);
      xs[(size_t)(r0+rr)*1024 + j] = f2b(yv * zv);
    }
  }
}

// ---------------- final rmsnorm + 3 heads (fp32) ----------------
__global__ __launch_bounds__(256) void k_heads(
    const float* __restrict__ h, const float* __restrict__ fnw,
    const float* __restrict__ act_w, const float* __restrict__ act_b,
    const float* __restrict__ comm_w, const float* __restrict__ comm_b,
    const float* __restrict__ val_w, const float* __restrict__ val_b,
    float* __restrict__ out)
{
  __shared__ float s_h[8][512];
  const int t = threadIdx.x;
  const int r0 = blockIdx.x * 8;
  const int r = t >> 5, lane = t & 31;
  float ss = 0.f;
  for (int k=lane;k<512;k+=32){ float v = h[(size_t)(r0+r)*512+k]; s_h[r][k]=v; ss=fmaf(v,v,ss); }
  #pragma unroll
  for (int m=16;m;m>>=1) ss += __shfl_xor(ss, m, 64);
  float rms = rsqrtf(ss*(1.f/512.f) + 1e-5f);
  for (int k=lane;k<512;k+=32) s_h[r][k] *= rms * fnw[k];
  __syncthreads();

  for (int i=t;i<8*133;i+=256) {
    int rr = i/133, o = i%133;
    if (o < 4) {
      float acc = act_b[o];
      for (int k=0;k<512;k++) acc = fmaf(s_h[rr][k], act_w[k*4+o], acc);
      out[(size_t)(r0+rr)*4 + o] = acc;
    } else if (o < 132) {
      int j = o-4;
      float acc = comm_b[j];
      for (int k=0;k<512;k++) acc = fmaf(s_h[rr][k], comm_w[k*128+j], acc);
      out[32768 + (size_t)(r0+rr)*128 + j] = tanhf(acc);
    } else {
      float acc = val_b[0];
      for (int k=0;k<512;k++) acc = fmaf(s_h[rr][k], val_w[k], acc);
      out[1081344 + (size_t)(r0+rr)] = acc;
    }
  }
}

extern "C" void kernel_launch(void* const* d_in, const int* in_sizes, int n_in,
                              void* d_out, int out_size, void* d_ws, size_t ws_size,
                              hipStream_t stream) {
  const float* obs       = (const float*)d_in[0];
  const float* comm_in   = (const float*)d_in[1];
  const float* conv_w    = (const float*)d_in[2];
  const float* conv_b    = (const float*)d_in[3];
  const float* enc_w     = (const float*)d_in[4];
  const float* enc_b     = (const float*)d_in[5];
  const float* proj_w    = (const float*)d_in[6];
  const float* proj_b    = (const float*)d_in[7];
  const float* norm_w    = (const float*)d_in[8];
  const float* in_proj_w = (const float*)d_in[9];
  const float* conv1d_w  = (const float*)d_in[10];
  const float* conv1d_b  = (const float*)d_in[11];
  const float* x_proj_w  = (const float*)d_in[12];
  const float* dt_proj_w = (const float*)d_in[13];
  const float* dt_proj_b = (const float*)d_in[14];
  // d_in[15] = A_log: dead at L=1
  const float* D_param   = (const float*)d_in[16];
  const float* out_proj_w= (const float*)d_in[17];
  const float* final_nw  = (const float*)d_in[18];
  const float* act_w     = (const float*)d_in[19];
  const float* act_b     = (const float*)d_in[20];
  const float* comm_w    = (const float*)d_in[21];
  const float* comm_b    = (const float*)d_in[22];
  const float* val_w     = (const float*)d_in[23];
  const float* val_b     = (const float*)d_in[24];
  float* out = (float*)d_out;

  char* W = (char*)d_ws;
  float* h             = (float*)W;                               // 16 MB
  unsigned short* u_b  = (unsigned short*)(W + (16u<<20));        //  8 MB
  unsigned short* xs_b = (unsigned short*)(W + (24u<<20));        // 16 MB (reused as g)
  unsigned short* zs_b = (unsigned short*)(W + (40u<<20));        // 16 MB
  unsigned short* wi_t = (unsigned short*)(W + (56u<<20));        //  4 MB (2 layers, [2048][512])
  unsigned short* wo_t = (unsigned short*)(W + (60u<<20));        //  2 MB (2 layers, [512][1024])

  // per-launch weight transpose-convert (fp32 [K][N] -> bf16 [N][K])
  k_wt<<<dim3(16,64),256,0,stream>>>(in_proj_w,              wi_t,             512, 2048);
  k_wt<<<dim3(16,64),256,0,stream>>>(in_proj_w + 512*2048,   wi_t + 2048*512,  512, 2048);
  k_wt<<<dim3(32,16),256,0,stream>>>(out_proj_w,             wo_t,            1024,  512);
  k_wt<<<dim3(32,16),256,0,stream>>>(out_proj_w + 1024*512,  wo_t + 512*1024, 1024,  512);

  k_frontend<<<1024,256,0,stream>>>(obs, comm_in, conv_w, conv_b, enc_w, enc_b, proj_w, proj_b, h);
  for (int L=0; L<2; L++) {
    k_rms<<<2048,256,0,stream>>>(h, norm_w + L*512, u_b);
    k_gemm_inproj<<<dim3(64,16),256,0,stream>>>(u_b, wi_t + (size_t)L*2048*512,
                                                conv1d_w + L*1024*4, conv1d_b + L*1024, xs_b, zs_b);
    k_ssm<<<1024,256,0,stream>>>(xs_b, zs_b, x_proj_w + (size_t)L*1024*64,
                                 dt_proj_w + (size_t)L*32*1024, dt_proj_b + L*1024,
                                 D_param + L*1024);
    k_gemm_outproj<<<dim3(64,4),256,0,stream>>>(xs_b, wo_t + (size_t)L*512*1024, h);
  }
  k_heads<<<1024,256,0,stream>>>(h, final_nw, act_w, act_b, comm_w, comm_b, val_w, val_b, out);
}

// Round 3
// 401.825 us; speedup vs baseline: 3.1320x; 1.4259x over previous
//
#include <hip/hip_runtime.h>
#include <math.h>

// SymNet fused model. L=1 collapses the mamba block to:
//   u = rmsnorm(h); xz = u@Wi; x = silu(xz[:,:1024]*cw[:,3]+cb); z' = silu(xz[:,1024:])
//   xdbl = x@Wx; dt = softplus(xdbl[:,:32]@Wdt + bdt); bc = dot(xdbl[:,32:48], xdbl[:,48:64])
//   g = x*(dt*bc + D) * z'; h += g@Wo
// A_log (dA) is dead code: dA multiplies h0 == 0.
// R3: heads + x_proj on MFMA; dt_proj via transposed bf16 weights (coalesced).

typedef __bf16 bf16x8 __attribute__((ext_vector_type(8)));
typedef float f32x4 __attribute__((ext_vector_type(4)));
typedef short short8 __attribute__((ext_vector_type(8)));

__device__ __forceinline__ float siluf(float v){ return v / (1.f + __expf(-v)); }
__device__ __forceinline__ float softplusf(float v){ return v > 20.f ? v : log1pf(__expf(v)); }
__device__ __forceinline__ float b2f(unsigned short u){ return __uint_as_float(((unsigned)u)<<16); }
__device__ __forceinline__ unsigned short f2b(float f){
  unsigned u = __float_as_uint(f);
  return (unsigned short)((u + 0x7fffu + ((u>>16)&1u)) >> 16);
}
__device__ __forceinline__ void g2l16(const void* g, void* l){
  __builtin_amdgcn_global_load_lds((const __attribute__((address_space(1))) unsigned int*)g,
                                   (__attribute__((address_space(3))) unsigned int*)l, 16, 0, 0);
}

// ---------------- weight transpose-convert: W fp32 [Kd][Nd] -> Wt bf16 [Nd][Kd] ----------------
__global__ __launch_bounds__(256) void k_wt(const float* __restrict__ W,
                                            unsigned short* __restrict__ Wt, int Kd, int Nd)
{
  __shared__ float s[32][33];
  const int kb = blockIdx.x*32, nb = blockIdx.y*32;
  const int c = threadIdx.x & 31, r = threadIdx.x >> 5;   // r = 0..7
  #pragma unroll
  for (int i=0;i<32;i+=8) s[r+i][c] = W[(size_t)(kb+r+i)*Nd + nb + c];
  __syncthreads();
  #pragma unroll
  for (int i=0;i<32;i+=8) Wt[(size_t)(nb+r+i)*Kd + kb + c] = f2b(s[c][r+i]);
}

// heads weight concat+transpose: Wh_t[256][512] bf16, rows: 0..3 act, 4..131 comm, 132 val, rest 0
__global__ __launch_bounds__(256) void k_wt_heads(
    const float* __restrict__ aw, const float* __restrict__ cw,
    const float* __restrict__ vw, unsigned short* __restrict__ Wt)
{
  const int n = blockIdx.x;
  for (int k = threadIdx.x; k < 512; k += 256) {
    float v;
    if (n < 4)        v = aw[k*4 + n];
    else if (n < 132) v = cw[k*128 + (n-4)];
    else if (n == 132)v = vw[k];
    else              v = 0.f;
    Wt[(size_t)n*512 + k] = f2b(v);
  }
}

// ---------------- rmsnorm -> bf16 (one row per wave) ----------------
__global__ __launch_bounds__(256) void k_rms(const float* __restrict__ h,
                                             const float* __restrict__ nw,
                                             unsigned short* __restrict__ u)
{
  const int l = threadIdx.x & 63;
  const size_t row = (size_t)blockIdx.x*4 + (threadIdx.x>>6);
  const float4* hp = (const float4*)(h + row*512) + l*2;
  float4 v0 = hp[0], v1 = hp[1];
  float ss = v0.x*v0.x+v0.y*v0.y+v0.z*v0.z+v0.w*v0.w
           + v1.x*v1.x+v1.y*v1.y+v1.z*v1.z+v1.w*v1.w;
  #pragma unroll
  for (int m=32;m;m>>=1) ss += __shfl_xor(ss, m, 64);
  const float sc = rsqrtf(ss*(1.f/512.f) + 1e-5f);
  const float4* np = (const float4*)nw + l*2;
  float4 w0 = np[0], w1 = np[1];
  short8 o;
  o[0]=(short)f2b(v0.x*sc*w0.x); o[1]=(short)f2b(v0.y*sc*w0.y);
  o[2]=(short)f2b(v0.z*sc*w0.z); o[3]=(short)f2b(v0.w*sc*w0.w);
  o[4]=(short)f2b(v1.x*sc*w1.x); o[5]=(short)f2b(v1.y*sc*w1.y);
  o[6]=(short)f2b(v1.z*sc*w1.z); o[7]=(short)f2b(v1.w*sc*w1.w);
  *(short8*)(u + row*512 + l*8) = o;
}

// ---------------- MFMA 128x128 tile mainloop (A [M][K] bf16, Bt [N][K] bf16) ----------------
template<int K>
__device__ __forceinline__ void gemm128(const unsigned short* __restrict__ A,
                                        const unsigned short* __restrict__ Bt,
                                        int r0, int c0,
                                        unsigned short* sA, unsigned short* sB,
                                        f32x4 acc[4][4])
{
  const int tid = threadIdx.x;
  const int l = tid & 63;
  const int wr = (tid>>7)&1, wc = (tid>>6)&1;
  const int rowA = tid>>3, kc8 = (tid&7)*8;
  const unsigned short* gA = A  + (size_t)(r0+rowA)*K + kc8;
  const unsigned short* gB = Bt + (size_t)(c0+rowA)*K + kc8;
  const int aOff = (wr*64 + (l&15))*64 + ((l>>4)*8);
  const int bOff = (wc*64 + (l&15))*64 + ((l>>4)*8);
  for (int kt=0; kt<K; kt+=64) {
    #pragma unroll
    for (int it=0; it<4; ++it) {
      g2l16(gA + (size_t)(it*32)*K + kt, sA + ((it*256+tid)*8));
      g2l16(gB + (size_t)(it*32)*K + kt, sB + ((it*256+tid)*8));
    }
    __syncthreads();
    #pragma unroll
    for (int ks=0; ks<64; ks+=32) {
      bf16x8 af[4], bfm[4];
      #pragma unroll
      for (int m=0;m<4;m++) af[m]  = *(const bf16x8*)(sA + (m*16)*64 + aOff + ks);
      #pragma unroll
      for (int n=0;n<4;n++) bfm[n] = *(const bf16x8*)(sB + (n*16)*64 + bOff + ks);
      #pragma unroll
      for (int m=0;m<4;m++)
        #pragma unroll
        for (int n=0;n<4;n++)
          acc[m][n] = __builtin_amdgcn_mfma_f32_16x16x32_bf16(af[m], bfm[n], acc[m][n], 0, 0, 0);
    }
    __syncthreads();
  }
}

// ---------------- in_proj: u_b(8192x512) @ Wi -> silu/conv-collapse -> xs,zs bf16 ----------------
__global__ __launch_bounds__(256) void k_gemm_inproj(
    const unsigned short* __restrict__ A, const unsigned short* __restrict__ Bt,
    const float* __restrict__ cw, const float* __restrict__ cb,
    unsigned short* __restrict__ xs, unsigned short* __restrict__ zs)
{
  __shared__ unsigned short sA[128*64], sB[128*64];
  f32x4 acc[4][4];
  #pragma unroll
  for (int m=0;m<4;m++)
    #pragma unroll
    for (int n=0;n<4;n++) acc[m][n] = (f32x4){0.f,0.f,0.f,0.f};
  const int r0 = blockIdx.x*128, c0 = blockIdx.y*128;
  gemm128<512>(A, Bt, r0, c0, sA, sB, acc);

  const int tid = threadIdx.x, l = tid & 63;
  const int wr = (tid>>7)&1, wc = (tid>>6)&1;
  const int colB = c0 + wc*64 + (l&15);
  const int rowB = r0 + wr*64 + ((l>>4)*4);
  if (c0 < 1024) {
    #pragma unroll
    for (int n=0;n<4;n++){
      const int col = colB + n*16;
      const float cw3 = cw[col*4+3], cbv = cb[col];
      #pragma unroll
      for (int m=0;m<4;m++)
        #pragma unroll
        for (int j=0;j<4;j++){
          const int row = rowB + m*16 + j;
          xs[(size_t)row*1024 + col] = f2b(siluf(fmaf(acc[m][n][j], cw3, cbv)));
        }
    }
  } else {
    #pragma unroll
    for (int n=0;n<4;n++){
      const int col = colB + n*16 - 1024;
      #pragma unroll
      for (int m=0;m<4;m++)
        #pragma unroll
        for (int j=0;j<4;j++){
          const int row = rowB + m*16 + j;
          zs[(size_t)row*1024 + col] = f2b(siluf(acc[m][n][j]));
        }
    }
  }
}

// ---------------- out_proj: g(8192x1024) @ Wo -> h += ----------------
__global__ __launch_bounds__(256) void k_gemm_outproj(
    const unsigned short* __restrict__ A, const unsigned short* __restrict__ Bt,
    float* __restrict__ h)
{
  __shared__ unsigned short sA[128*64], sB[128*64];
  f32x4 acc[4][4];
  #pragma unroll
  for (int m=0;m<4;m++)
    #pragma unroll
    for (int n=0;n<4;n++) acc[m][n] = (f32x4){0.f,0.f,0.f,0.f};
  const int r0 = blockIdx.x*128, c0 = blockIdx.y*128;
  gemm128<1024>(A, Bt, r0, c0, sA, sB, acc);

  const int tid = threadIdx.x, l = tid & 63;
  const int wr = (tid>>7)&1, wc = (tid>>6)&1;
  const int colB = c0 + wc*64 + (l&15);
  const int rowB = r0 + wr*64 + ((l>>4)*4);
  #pragma unroll
  for (int n=0;n<4;n++){
    const int col = colB + n*16;
    #pragma unroll
    for (int m=0;m<4;m++)
      #pragma unroll
      for (int j=0;j<4;j++){
        const int row = rowB + m*16 + j;
        h[(size_t)row*512 + col] += acc[m][n][j];
      }
  }
}

// ---------------- heads GEMM: u(8192x512) @ Wh_t^T -> act/tanh(comm)/val scatter ----------------
__global__ __launch_bounds__(256) void k_gemm_heads(
    const unsigned short* __restrict__ A, const unsigned short* __restrict__ Bt,
    const float* __restrict__ act_b, const float* __restrict__ comm_b,
    const float* __restrict__ val_b, float* __restrict__ out)
{
  __shared__ unsigned short sA[128*64], sB[128*64];
  f32x4 acc[4][4];
  #pragma unroll
  for (int m=0;m<4;m++)
    #pragma unroll
    for (int n=0;n<4;n++) acc[m][n] = (f32x4){0.f,0.f,0.f,0.f};
  const int r0 = blockIdx.x*128, c0 = blockIdx.y*128;
  gemm128<512>(A, Bt, r0, c0, sA, sB, acc);

  const int tid = threadIdx.x, l = tid & 63;
  const int wr = (tid>>7)&1, wc = (tid>>6)&1;
  const int colB = c0 + wc*64 + (l&15);
  const int rowB = r0 + wr*64 + ((l>>4)*4);
  #pragma unroll
  for (int n=0;n<4;n++){
    const int col = colB + n*16;
    if (col > 132) continue;
    #pragma unroll
    for (int m=0;m<4;m++)
      #pragma unroll
      for (int j=0;j<4;j++){
        const size_t row = rowB + m*16 + j;
        float v = acc[m][n][j];
        if (col < 4)        out[row*4 + col] = v + act_b[col];
        else if (col < 132) out[32768 + row*128 + (col-4)] = tanhf(v + comm_b[col-4]);
        else                out[1081344 + row] = v + val_b[0];
      }
  }
}

// ---------------- x_dbl GEMM: xs(8192x1024) @ Wx_t^T(64x1024) -> xdbl fp32 ----------------
__global__ __launch_bounds__(256) void k_xdbl(
    const unsigned short* __restrict__ A, const unsigned short* __restrict__ Bt,
    float* __restrict__ xdbl)
{
  __shared__ unsigned short sA[128*64], sB[64*64];
  f32x4 acc[2][4];
  #pragma unroll
  for (int m=0;m<2;m++)
    #pragma unroll
    for (int n=0;n<4;n++) acc[m][n] = (f32x4){0.f,0.f,0.f,0.f};
  const int tid = threadIdx.x, l = tid & 63, w = tid>>6;
  const int r0 = blockIdx.x*128;
  const int rowA = tid>>3, kc8 = (tid&7)*8;
  const unsigned short* gA = A  + (size_t)(r0+rowA)*1024 + kc8;
  const unsigned short* gB = Bt + (size_t)rowA*1024 + kc8;
  const int aOff = (w*32 + (l&15))*64 + ((l>>4)*8);
  const int bOff = ((l&15))*64 + ((l>>4)*8);
  for (int kt=0; kt<1024; kt+=64) {
    #pragma unroll
    for (int it=0; it<4; ++it) g2l16(gA + (size_t)(it*32)*1024 + kt, sA + (it*256+tid)*8);
    #pragma unroll
    for (int it=0; it<2; ++it) g2l16(gB + (size_t)(it*32)*1024 + kt, sB + (it*256+tid)*8);
    __syncthreads();
    #pragma unroll
    for (int ks=0; ks<64; ks+=32) {
      bf16x8 af[2], bfm[4];
      #pragma unroll
      for (int m=0;m<2;m++) af[m]  = *(const bf16x8*)(sA + (m*16)*64 + aOff + ks);
      #pragma unroll
      for (int n=0;n<4;n++) bfm[n] = *(const bf16x8*)(sB + (n*16)*64 + bOff + ks);
      #pragma unroll
      for (int m=0;m<2;m++)
        #pragma unroll
        for (int n=0;n<4;n++)
          acc[m][n] = __builtin_amdgcn_mfma_f32_16x16x32_bf16(af[m], bfm[n], acc[m][n], 0, 0, 0);
    }
    __syncthreads();
  }
  #pragma unroll
  for (int n=0;n<4;n++){
    const int col = n*16 + (l&15);
    #pragma unroll
    for (int m=0;m<2;m++)
      #pragma unroll
      for (int j=0;j<4;j++){
        const size_t row = r0 + w*32 + m*16 + (l>>4)*4 + j;
        xdbl[row*64 + col] = acc[m][n][j];
      }
  }
}

// ---------------- frontend: conv2d + enc + proj -> h (B,512) fp32 ----------------
__global__ __launch_bounds__(256) void k_frontend(
    const float* __restrict__ obs, const float* __restrict__ comm_in,
    const float* __restrict__ conv_w, const float* __restrict__ conv_b,
    const float* __restrict__ enc_w, const float* __restrict__ enc_b,
    const float* __restrict__ proj_w, const float* __restrict__ proj_b,
    float* __restrict__ h)
{
  __shared__ float s_obs[8][76];
  __shared__ float s_v[8][288];
  __shared__ float s_cat[8][384];
  const int t = threadIdx.x;
  const int r0 = blockIdx.x * 8;

  for (int i = t; i < 8*75; i += 256) s_obs[i/75][i%75] = obs[(size_t)(r0 + i/75)*75 + i%75];
  __syncthreads();

  for (int i = t; i < 8*288; i += 256) {
    int r = i / 288, o = i % 288;
    int c = o / 9, ij = o % 9, oi = ij/3, oj = ij%3;
    float acc = conv_b[c];
    #pragma unroll
    for (int ic=0; ic<3; ic++)
      #pragma unroll
      for (int ki=0; ki<3; ki++)
        #pragma unroll
        for (int kj=0; kj<3; kj++)
          acc = fmaf(s_obs[r][ic*25 + (oi+ki)*5 + (oj+kj)], conv_w[((c*3+ic)*3+ki)*3+kj], acc);
    s_v[r][o] = fmaxf(acc, 0.f);
  }
  __syncthreads();

  {
    float acc[8];
    #pragma unroll
    for (int r=0;r<8;r++) acc[r] = enc_b[t];
    for (int k=0;k<288;k++) {
      float w = enc_w[k*256 + t];
      #pragma unroll
      for (int r=0;r<8;r++) acc[r] = fmaf(s_v[r][k], w, acc[r]);
    }
    #pragma unroll
    for (int r=0;r<8;r++) s_cat[r][t] = fmaxf(acc[r], 0.f);
  }
  for (int i = t; i < 8*128; i += 256) s_cat[i/128][256 + i%128] = comm_in[(size_t)(r0 + i/128)*128 + i%128];
  __syncthreads();

  {
    float a0[8], a1[8];
    #pragma unroll
    for (int r=0;r<8;r++){ a0[r]=proj_b[t]; a1[r]=proj_b[t+256]; }
    for (int k=0;k<384;k++) {
      float w0 = proj_w[k*512 + t];
      float w1 = proj_w[k*512 + t + 256];
      #pragma unroll
      for (int r=0;r<8;r++){ float v = s_cat[r][k]; a0[r]=fmaf(v,w0,a0[r]); a1[r]=fmaf(v,w1,a1[r]); }
    }
    #pragma unroll
    for (int r=0;r<8;r++){
      h[(size_t)(r0+r)*512 + t]       = fmaxf(a0[r], 0.f);
      h[(size_t)(r0+r)*512 + t + 256] = fmaxf(a1[r], 0.f);
    }
  }
}

// ---------------- SSM tail: bc, dt (bf16 Wdt_t), gate -> g (bf16, into xs) ----------------
__global__ __launch_bounds__(256) void k_ssm2(
    unsigned short* __restrict__ xs, const unsigned short* __restrict__ zs,
    const float* __restrict__ xdbl, const unsigned short* __restrict__ Wdt_t,
    const float* __restrict__ bdt, const float* __restrict__ Dp)
{
  __shared__ float s_dbl[8][64];
  __shared__ float s_bc[8];
  const int t = threadIdx.x;
  const int r0 = blockIdx.x * 8;

  for (int i=t; i<512; i+=256) s_dbl[i>>6][i&63] = xdbl[(size_t)r0*64 + i];
  __syncthreads();
  if (t < 8) {
    float acc=0.f;
    #pragma unroll
    for (int s=0;s<16;s++) acc = fmaf(s_dbl[t][32+s], s_dbl[t][48+s], acc);
    s_bc[t] = acc;
  }
  __syncthreads();

  #pragma unroll
  for (int c=0;c<4;c++) {
    const int j = t + c*256;
    float w[32];
    {
      const short8* wp = (const short8*)(Wdt_t + (size_t)j*32);
      #pragma unroll
      for (int q=0;q<4;q++){
        short8 v = wp[q];
        #pragma unroll
        for (int e=0;e<8;e++) w[q*8+e] = b2f((unsigned short)v[e]);
      }
    }
    const float bj = bdt[j], dpj = Dp[j];
    #pragma unroll
    for (int rr=0;rr<8;rr++) {
      float acc = bj;
      #pragma unroll
      for (int k=0;k<32;k++) acc = fmaf(s_dbl[rr][k], w[k], acc);
      float dtv = softplusf(acc);
      float xv = b2f(xs[(size_t)(r0+rr)*1024 + j]);
      float yv = xv * fmaf(dtv, s_bc[rr], dpj);
      float zv = b2f(zs[(size_t)(r0+rr)*1024 + j]);
      xs[(size_t)(r0+rr)*1024 + j] = f2b(yv * zv);
    }
  }
}

extern "C" void kernel_launch(void* const* d_in, const int* in_sizes, int n_in,
                              void* d_out, int out_size, void* d_ws, size_t ws_size,
                              hipStream_t stream) {
  const float* obs       = (const float*)d_in[0];
  const float* comm_in   = (const float*)d_in[1];
  const float* conv_w    = (const float*)d_in[2];
  const float* conv_b    = (const float*)d_in[3];
  const float* enc_w     = (const float*)d_in[4];
  const float* enc_b     = (const float*)d_in[5];
  const float* proj_w    = (const float*)d_in[6];
  const float* proj_b    = (const float*)d_in[7];
  const float* norm_w    = (const float*)d_in[8];
  const float* in_proj_w = (const float*)d_in[9];
  const float* conv1d_w  = (const float*)d_in[10];
  const float* conv1d_b  = (const float*)d_in[11];
  const float* x_proj_w  = (const float*)d_in[12];
  const float* dt_proj_w = (const float*)d_in[13];
  const float* dt_proj_b = (const float*)d_in[14];
  // d_in[15] = A_log: dead at L=1
  const float* D_param   = (const float*)d_in[16];
  const float* out_proj_w= (const float*)d_in[17];
  const float* final_nw  = (const float*)d_in[18];
  const float* act_w     = (const float*)d_in[19];
  const float* act_b     = (const float*)d_in[20];
  const float* comm_w    = (const float*)d_in[21];
  const float* comm_b    = (const float*)d_in[22];
  const float* val_w     = (const float*)d_in[23];
  const float* val_b     = (const float*)d_in[24];
  float* out = (float*)d_out;

  char* W = (char*)d_ws;
  float* h             = (float*)W;                               // 16 MB
  unsigned short* u_b  = (unsigned short*)(W + (16u<<20));        //  8 MB
  unsigned short* xs_b = (unsigned short*)(W + (24u<<20));        // 16 MB (reused as g)
  unsigned short* zs_b = (unsigned short*)(W + (40u<<20));        // 16 MB
  unsigned short* wi_t = (unsigned short*)(W + (56u<<20));        //  4 MB (2 layers, [2048][512])
  unsigned short* wo_t = (unsigned short*)(W + (60u<<20));        //  2 MB (2 layers, [512][1024])
  float* xdbl          = (float*)(W + (62u<<20));                 //  2 MB [8192][64]
  unsigned short* wx_t = (unsigned short*)(W + (64u<<20));        // 256 KB (2 layers, [64][1024])
  unsigned short* wdt_t= (unsigned short*)(W + (64u<<20) + (256u<<10)); // 128 KB (2 layers, [1024][32])
  unsigned short* wh_t = (unsigned short*)(W + (65u<<20));        // 256 KB [256][512]

  // per-launch weight transpose-converts (fp32 [K][N] -> bf16 [N][K])
  k_wt<<<dim3(16,64),256,0,stream>>>(in_proj_w,              wi_t,             512, 2048);
  k_wt<<<dim3(16,64),256,0,stream>>>(in_proj_w + 512*2048,   wi_t + 2048*512,  512, 2048);
  k_wt<<<dim3(32,16),256,0,stream>>>(out_proj_w,             wo_t,            1024,  512);
  k_wt<<<dim3(32,16),256,0,stream>>>(out_proj_w + 1024*512,  wo_t + 512*1024, 1024,  512);
  k_wt<<<dim3(32,2),256,0,stream>>>(x_proj_w,                wx_t,            1024,   64);
  k_wt<<<dim3(32,2),256,0,stream>>>(x_proj_w + 1024*64,      wx_t + 64*1024,  1024,   64);
  k_wt<<<dim3(1,32),256,0,stream>>>(dt_proj_w,               wdt_t,             32, 1024);
  k_wt<<<dim3(1,32),256,0,stream>>>(dt_proj_w + 32*1024,     wdt_t + 1024*32,   32, 1024);
  k_wt_heads<<<256,256,0,stream>>>(act_w, comm_w, val_w, wh_t);

  k_frontend<<<1024,256,0,stream>>>(obs, comm_in, conv_w, conv_b, enc_w, enc_b, proj_w, proj_b, h);
  for (int L=0; L<2; L++) {
    k_rms<<<2048,256,0,stream>>>(h, norm_w + L*512, u_b);
    k_gemm_inproj<<<dim3(64,16),256,0,stream>>>(u_b, wi_t + (size_t)L*2048*512,
                                                conv1d_w + L*1024*4, conv1d_b + L*1024, xs_b, zs_b);
    k_xdbl<<<64,256,0,stream>>>(xs_b, wx_t + (size_t)L*64*1024, xdbl);
    k_ssm2<<<1024,256,0,stream>>>(xs_b, zs_b, xdbl, wdt_t + (size_t)L*1024*32,
                                  dt_proj_b + L*1024, D_param + L*1024);
    k_gemm_outproj<<<dim3(64,4),256,0,stream>>>(xs_b, wo_t + (size_t)L*512*1024, h);
  }
  k_rms<<<2048,256,0,stream>>>(h, final_nw, u_b);
  k_gemm_heads<<<dim3(64,2),256,0,stream>>>(u_b, wh_t, act_b, comm_b, val_b, out);
}

// Round 4
// 345.920 us; speedup vs baseline: 3.6381x; 1.1616x over previous
//
#include <hip/hip_runtime.h>
#include <math.h>

// SymNet fused model. L=1 collapses the mamba block to:
//   u = rmsnorm(h); xz = u@Wi; x = silu(xz[:,:1024]*cw[:,3]+cb); z' = silu(xz[:,1024:])
//   xdbl = x@Wx; dt = softplus(xdbl[:,:32]@Wdt + bdt); bc = dot(xdbl[:,32:48], xdbl[:,48:64])
//   g = x*(dt*bc + D) * z'; h += g@Wo
// A_log (dA) is dead code: dA multiplies h0 == 0.
// R4: frontend enc/proj GEMMs moved to bf16 MFMA (conv stays scalar, K padded 288->320).

typedef __bf16 bf16x8 __attribute__((ext_vector_type(8)));
typedef float f32x4 __attribute__((ext_vector_type(4)));
typedef short short8 __attribute__((ext_vector_type(8)));

__device__ __forceinline__ float siluf(float v){ return v / (1.f + __expf(-v)); }
__device__ __forceinline__ float softplusf(float v){ return v > 20.f ? v : log1pf(__expf(v)); }
__device__ __forceinline__ float b2f(unsigned short u){ return __uint_as_float(((unsigned)u)<<16); }
__device__ __forceinline__ unsigned short f2b(float f){
  unsigned u = __float_as_uint(f);
  return (unsigned short)((u + 0x7fffu + ((u>>16)&1u)) >> 16);
}
__device__ __forceinline__ void g2l16(const void* g, void* l){
  __builtin_amdgcn_global_load_lds((const __attribute__((address_space(1))) unsigned int*)g,
                                   (__attribute__((address_space(3))) unsigned int*)l, 16, 0, 0);
}

// ---------------- weight transpose-convert: W fp32 [Kd][Nd] -> Wt bf16 [Nd][Kd] ----------------
__global__ __launch_bounds__(256) void k_wt(const float* __restrict__ W,
                                            unsigned short* __restrict__ Wt, int Kd, int Nd)
{
  __shared__ float s[32][33];
  const int kb = blockIdx.x*32, nb = blockIdx.y*32;
  const int c = threadIdx.x & 31, r = threadIdx.x >> 5;   // r = 0..7
  #pragma unroll
  for (int i=0;i<32;i+=8) s[r+i][c] = W[(size_t)(kb+r+i)*Nd + nb + c];
  __syncthreads();
  #pragma unroll
  for (int i=0;i<32;i+=8) Wt[(size_t)(nb+r+i)*Kd + kb + c] = f2b(s[c][r+i]);
}

// same, but output row-stride KP >= Kd with zero pad (for K not multiple of 64)
__global__ __launch_bounds__(256) void k_wt_pad(const float* __restrict__ W,
                                                unsigned short* __restrict__ Wt,
                                                int Kd, int Nd, int KP)
{
  __shared__ float s[32][33];
  const int kb = blockIdx.x*32, nb = blockIdx.y*32;
  const int c = threadIdx.x & 31, r = threadIdx.x >> 5;
  #pragma unroll
  for (int i=0;i<32;i+=8) {
    const int k = kb + r + i;
    s[r+i][c] = (k < Kd) ? W[(size_t)k*Nd + nb + c] : 0.f;
  }
  __syncthreads();
  #pragma unroll
  for (int i=0;i<32;i+=8) Wt[(size_t)(nb+r+i)*KP + kb + c] = f2b(s[c][r+i]);
}

// heads weight concat+transpose: Wh_t[256][512] bf16, rows: 0..3 act, 4..131 comm, 132 val, rest 0
__global__ __launch_bounds__(256) void k_wt_heads(
    const float* __restrict__ aw, const float* __restrict__ cw,
    const float* __restrict__ vw, unsigned short* __restrict__ Wt)
{
  const int n = blockIdx.x;
  for (int k = threadIdx.x; k < 512; k += 256) {
    float v;
    if (n < 4)        v = aw[k*4 + n];
    else if (n < 132) v = cw[k*128 + (n-4)];
    else if (n == 132)v = vw[k];
    else              v = 0.f;
    Wt[(size_t)n*512 + k] = f2b(v);
  }
}

// ---------------- rmsnorm -> bf16 (one row per wave) ----------------
__global__ __launch_bounds__(256) void k_rms(const float* __restrict__ h,
                                             const float* __restrict__ nw,
                                             unsigned short* __restrict__ u)
{
  const int l = threadIdx.x & 63;
  const size_t row = (size_t)blockIdx.x*4 + (threadIdx.x>>6);
  const float4* hp = (const float4*)(h + row*512) + l*2;
  float4 v0 = hp[0], v1 = hp[1];
  float ss = v0.x*v0.x+v0.y*v0.y+v0.z*v0.z+v0.w*v0.w
           + v1.x*v1.x+v1.y*v1.y+v1.z*v1.z+v1.w*v1.w;
  #pragma unroll
  for (int m=32;m;m>>=1) ss += __shfl_xor(ss, m, 64);
  const float sc = rsqrtf(ss*(1.f/512.f) + 1e-5f);
  const float4* np = (const float4*)nw + l*2;
  float4 w0 = np[0], w1 = np[1];
  short8 o;
  o[0]=(short)f2b(v0.x*sc*w0.x); o[1]=(short)f2b(v0.y*sc*w0.y);
  o[2]=(short)f2b(v0.z*sc*w0.z); o[3]=(short)f2b(v0.w*sc*w0.w);
  o[4]=(short)f2b(v1.x*sc*w1.x); o[5]=(short)f2b(v1.y*sc*w1.y);
  o[6]=(short)f2b(v1.z*sc*w1.z); o[7]=(short)f2b(v1.w*sc*w1.w);
  *(short8*)(u + row*512 + l*8) = o;
}

// ---------------- MFMA 128x128 tile mainloop (A [M][K] bf16, Bt [N][K] bf16) ----------------
template<int K>
__device__ __forceinline__ void gemm128(const unsigned short* __restrict__ A,
                                        const unsigned short* __restrict__ Bt,
                                        int r0, int c0,
                                        unsigned short* sA, unsigned short* sB,
                                        f32x4 acc[4][4])
{
  const int tid = threadIdx.x;
  const int l = tid & 63;
  const int wr = (tid>>7)&1, wc = (tid>>6)&1;
  const int rowA = tid>>3, kc8 = (tid&7)*8;
  const unsigned short* gA = A  + (size_t)(r0+rowA)*K + kc8;
  const unsigned short* gB = Bt + (size_t)(c0+rowA)*K + kc8;
  const int aOff = (wr*64 + (l&15))*64 + ((l>>4)*8);
  const int bOff = (wc*64 + (l&15))*64 + ((l>>4)*8);
  for (int kt=0; kt<K; kt+=64) {
    #pragma unroll
    for (int it=0; it<4; ++it) {
      g2l16(gA + (size_t)(it*32)*K + kt, sA + ((it*256+tid)*8));
      g2l16(gB + (size_t)(it*32)*K + kt, sB + ((it*256+tid)*8));
    }
    __syncthreads();
    #pragma unroll
    for (int ks=0; ks<64; ks+=32) {
      bf16x8 af[4], bfm[4];
      #pragma unroll
      for (int m=0;m<4;m++) af[m]  = *(const bf16x8*)(sA + (m*16)*64 + aOff + ks);
      #pragma unroll
      for (int n=0;n<4;n++) bfm[n] = *(const bf16x8*)(sB + (n*16)*64 + bOff + ks);
      #pragma unroll
      for (int m=0;m<4;m++)
        #pragma unroll
        for (int n=0;n<4;n++)
          acc[m][n] = __builtin_amdgcn_mfma_f32_16x16x32_bf16(af[m], bfm[n], acc[m][n], 0, 0, 0);
    }
    __syncthreads();
  }
}

// ---------------- in_proj: u_b(8192x512) @ Wi -> silu/conv-collapse -> xs,zs bf16 ----------------
__global__ __launch_bounds__(256) void k_gemm_inproj(
    const unsigned short* __restrict__ A, const unsigned short* __restrict__ Bt,
    const float* __restrict__ cw, const float* __restrict__ cb,
    unsigned short* __restrict__ xs, unsigned short* __restrict__ zs)
{
  __shared__ unsigned short sA[128*64], sB[128*64];
  f32x4 acc[4][4];
  #pragma unroll
  for (int m=0;m<4;m++)
    #pragma unroll
    for (int n=0;n<4;n++) acc[m][n] = (f32x4){0.f,0.f,0.f,0.f};
  const int r0 = blockIdx.x*128, c0 = blockIdx.y*128;
  gemm128<512>(A, Bt, r0, c0, sA, sB, acc);

  const int tid = threadIdx.x, l = tid & 63;
  const int wr = (tid>>7)&1, wc = (tid>>6)&1;
  const int colB = c0 + wc*64 + (l&15);
  const int rowB = r0 + wr*64 + ((l>>4)*4);
  if (c0 < 1024) {
    #pragma unroll
    for (int n=0;n<4;n++){
      const int col = colB + n*16;
      const float cw3 = cw[col*4+3], cbv = cb[col];
      #pragma unroll
      for (int m=0;m<4;m++)
        #pragma unroll
        for (int j=0;j<4;j++){
          const int row = rowB + m*16 + j;
          xs[(size_t)row*1024 + col] = f2b(siluf(fmaf(acc[m][n][j], cw3, cbv)));
        }
    }
  } else {
    #pragma unroll
    for (int n=0;n<4;n++){
      const int col = colB + n*16 - 1024;
      #pragma unroll
      for (int m=0;m<4;m++)
        #pragma unroll
        for (int j=0;j<4;j++){
          const int row = rowB + m*16 + j;
          zs[(size_t)row*1024 + col] = f2b(siluf(acc[m][n][j]));
        }
    }
  }
}

// ---------------- out_proj: g(8192x1024) @ Wo -> h += ----------------
__global__ __launch_bounds__(256) void k_gemm_outproj(
    const unsigned short* __restrict__ A, const unsigned short* __restrict__ Bt,
    float* __restrict__ h)
{
  __shared__ unsigned short sA[128*64], sB[128*64];
  f32x4 acc[4][4];
  #pragma unroll
  for (int m=0;m<4;m++)
    #pragma unroll
    for (int n=0;n<4;n++) acc[m][n] = (f32x4){0.f,0.f,0.f,0.f};
  const int r0 = blockIdx.x*128, c0 = blockIdx.y*128;
  gemm128<1024>(A, Bt, r0, c0, sA, sB, acc);

  const int tid = threadIdx.x, l = tid & 63;
  const int wr = (tid>>7)&1, wc = (tid>>6)&1;
  const int colB = c0 + wc*64 + (l&15);
  const int rowB = r0 + wr*64 + ((l>>4)*4);
  #pragma unroll
  for (int n=0;n<4;n++){
    const int col = colB + n*16;
    #pragma unroll
    for (int m=0;m<4;m++)
      #pragma unroll
      for (int j=0;j<4;j++){
        const int row = rowB + m*16 + j;
        h[(size_t)row*512 + col] += acc[m][n][j];
      }
  }
}

// ---------------- frontend GEMM1: v(8192x320) @ enc_t^T -> relu -> cat[:, :256] ----------------
__global__ __launch_bounds__(256) void k_gemm_enc(
    const unsigned short* __restrict__ A, const unsigned short* __restrict__ Bt,
    const float* __restrict__ bias, unsigned short* __restrict__ cat)
{
  __shared__ unsigned short sA[128*64], sB[128*64];
  f32x4 acc[4][4];
  #pragma unroll
  for (int m=0;m<4;m++)
    #pragma unroll
    for (int n=0;n<4;n++) acc[m][n] = (f32x4){0.f,0.f,0.f,0.f};
  const int r0 = blockIdx.x*128, c0 = blockIdx.y*128;
  gemm128<320>(A, Bt, r0, c0, sA, sB, acc);

  const int tid = threadIdx.x, l = tid & 63;
  const int wr = (tid>>7)&1, wc = (tid>>6)&1;
  const int colB = c0 + wc*64 + (l&15);
  const int rowB = r0 + wr*64 + ((l>>4)*4);
  #pragma unroll
  for (int n=0;n<4;n++){
    const int col = colB + n*16;
    const float bv = bias[col];
    #pragma unroll
    for (int m=0;m<4;m++)
      #pragma unroll
      for (int j=0;j<4;j++){
        const size_t row = rowB + m*16 + j;
        cat[row*384 + col] = f2b(fmaxf(acc[m][n][j] + bv, 0.f));
      }
  }
}

// ---------------- frontend GEMM2: cat(8192x384) @ proj_t^T -> relu -> h fp32 ----------------
__global__ __launch_bounds__(256) void k_gemm_proj(
    const unsigned short* __restrict__ A, const unsigned short* __restrict__ Bt,
    const float* __restrict__ bias, float* __restrict__ h)
{
  __shared__ unsigned short sA[128*64], sB[128*64];
  f32x4 acc[4][4];
  #pragma unroll
  for (int m=0;m<4;m++)
    #pragma unroll
    for (int n=0;n<4;n++) acc[m][n] = (f32x4){0.f,0.f,0.f,0.f};
  const int r0 = blockIdx.x*128, c0 = blockIdx.y*128;
  gemm128<384>(A, Bt, r0, c0, sA, sB, acc);

  const int tid = threadIdx.x, l = tid & 63;
  const int wr = (tid>>7)&1, wc = (tid>>6)&1;
  const int colB = c0 + wc*64 + (l&15);
  const int rowB = r0 + wr*64 + ((l>>4)*4);
  #pragma unroll
  for (int n=0;n<4;n++){
    const int col = colB + n*16;
    const float bv = bias[col];
    #pragma unroll
    for (int m=0;m<4;m++)
      #pragma unroll
      for (int j=0;j<4;j++){
        const size_t row = rowB + m*16 + j;
        h[row*512 + col] = fmaxf(acc[m][n][j] + bv, 0.f);
      }
  }
}

// ---------------- frontend prep: conv2d -> v bf16 [8192][320] (pad 0), comm -> cat[:,256:384] ----------------
__global__ __launch_bounds__(256) void k_front_prep(
    const float* __restrict__ obs, const float* __restrict__ comm_in,
    const float* __restrict__ conv_w, const float* __restrict__ conv_b,
    unsigned short* __restrict__ v, unsigned short* __restrict__ cat)
{
  __shared__ float s_obs[8][76];
  const int t = threadIdx.x;
  const int r0 = blockIdx.x * 8;

  for (int i = t; i < 8*75; i += 256) s_obs[i/75][i%75] = obs[(size_t)(r0 + i/75)*75 + i%75];
  __syncthreads();

  for (int i = t; i < 8*288; i += 256) {
    int r = i / 288, o = i % 288;
    int c = o / 9, ij = o % 9, oi = ij/3, oj = ij%3;
    float acc = conv_b[c];
    #pragma unroll
    for (int ic=0; ic<3; ic++)
      #pragma unroll
      for (int ki=0; ki<3; ki++)
        #pragma unroll
        for (int kj=0; kj<3; kj++)
          acc = fmaf(s_obs[r][ic*25 + (oi+ki)*5 + (oj+kj)], conv_w[((c*3+ic)*3+ki)*3+kj], acc);
    v[(size_t)(r0+r)*320 + o] = f2b(fmaxf(acc, 0.f));
  }
  // zero pad cols 288..319 (8 rows x 32 cols = 256)
  v[(size_t)(r0 + (t>>5))*320 + 288 + (t&31)] = 0;
  // comm -> cat[:, 256:384]
  for (int i = t; i < 8*128; i += 256) {
    int r = i >> 7, c = i & 127;
    cat[(size_t)(r0+r)*384 + 256 + c] = f2b(comm_in[(size_t)(r0+r)*128 + c]);
  }
}

// ---------------- heads GEMM: u(8192x512) @ Wh_t^T -> act/tanh(comm)/val scatter ----------------
__global__ __launch_bounds__(256) void k_gemm_heads(
    const unsigned short* __restrict__ A, const unsigned short* __restrict__ Bt,
    const float* __restrict__ act_b, const float* __restrict__ comm_b,
    const float* __restrict__ val_b, float* __restrict__ out)
{
  __shared__ unsigned short sA[128*64], sB[128*64];
  f32x4 acc[4][4];
  #pragma unroll
  for (int m=0;m<4;m++)
    #pragma unroll
    for (int n=0;n<4;n++) acc[m][n] = (f32x4){0.f,0.f,0.f,0.f};
  const int r0 = blockIdx.x*128, c0 = blockIdx.y*128;
  gemm128<512>(A, Bt, r0, c0, sA, sB, acc);

  const int tid = threadIdx.x, l = tid & 63;
  const int wr = (tid>>7)&1, wc = (tid>>6)&1;
  const int colB = c0 + wc*64 + (l&15);
  const int rowB = r0 + wr*64 + ((l>>4)*4);
  #pragma unroll
  for (int n=0;n<4;n++){
    const int col = colB + n*16;
    if (col > 132) continue;
    #pragma unroll
    for (int m=0;m<4;m++)
      #pragma unroll
      for (int j=0;j<4;j++){
        const size_t row = rowB + m*16 + j;
        float v = acc[m][n][j];
        if (col < 4)        out[row*4 + col] = v + act_b[col];
        else if (col < 132) out[32768 + row*128 + (col-4)] = tanhf(v + comm_b[col-4]);
        else                out[1081344 + row] = v + val_b[0];
      }
  }
}

// ---------------- x_dbl GEMM: xs(8192x1024) @ Wx_t^T(64x1024) -> xdbl fp32 ----------------
__global__ __launch_bounds__(256) void k_xdbl(
    const unsigned short* __restrict__ A, const unsigned short* __restrict__ Bt,
    float* __restrict__ xdbl)
{
  __shared__ unsigned short sA[128*64], sB[64*64];
  f32x4 acc[2][4];
  #pragma unroll
  for (int m=0;m<2;m++)
    #pragma unroll
    for (int n=0;n<4;n++) acc[m][n] = (f32x4){0.f,0.f,0.f,0.f};
  const int tid = threadIdx.x, l = tid & 63, w = tid>>6;
  const int r0 = blockIdx.x*128;
  const int rowA = tid>>3, kc8 = (tid&7)*8;
  const unsigned short* gA = A  + (size_t)(r0+rowA)*1024 + kc8;
  const unsigned short* gB = Bt + (size_t)rowA*1024 + kc8;
  const int aOff = (w*32 + (l&15))*64 + ((l>>4)*8);
  const int bOff = ((l&15))*64 + ((l>>4)*8);
  for (int kt=0; kt<1024; kt+=64) {
    #pragma unroll
    for (int it=0; it<4; ++it) g2l16(gA + (size_t)(it*32)*1024 + kt, sA + (it*256+tid)*8);
    #pragma unroll
    for (int it=0; it<2; ++it) g2l16(gB + (size_t)(it*32)*1024 + kt, sB + (it*256+tid)*8);
    __syncthreads();
    #pragma unroll
    for (int ks=0; ks<64; ks+=32) {
      bf16x8 af[2], bfm[4];
      #pragma unroll
      for (int m=0;m<2;m++) af[m]  = *(const bf16x8*)(sA + (m*16)*64 + aOff + ks);
      #pragma unroll
      for (int n=0;n<4;n++) bfm[n] = *(const bf16x8*)(sB + (n*16)*64 + bOff + ks);
      #pragma unroll
      for (int m=0;m<2;m++)
        #pragma unroll
        for (int n=0;n<4;n++)
          acc[m][n] = __builtin_amdgcn_mfma_f32_16x16x32_bf16(af[m], bfm[n], acc[m][n], 0, 0, 0);
    }
    __syncthreads();
  }
  #pragma unroll
  for (int n=0;n<4;n++){
    const int col = n*16 + (l&15);
    #pragma unroll
    for (int m=0;m<2;m++)
      #pragma unroll
      for (int j=0;j<4;j++){
        const size_t row = r0 + w*32 + m*16 + (l>>4)*4 + j;
        xdbl[row*64 + col] = acc[m][n][j];
      }
  }
}

// ---------------- SSM tail: bc, dt (bf16 Wdt_t), gate -> g (bf16, into xs) ----------------
__global__ __launch_bounds__(256) void k_ssm2(
    unsigned short* __restrict__ xs, const unsigned short* __restrict__ zs,
    const float* __restrict__ xdbl, const unsigned short* __restrict__ Wdt_t,
    const float* __restrict__ bdt, const float* __restrict__ Dp)
{
  __shared__ float s_dbl[8][64];
  __shared__ float s_bc[8];
  const int t = threadIdx.x;
  const int r0 = blockIdx.x * 8;

  for (int i=t; i<512; i+=256) s_dbl[i>>6][i&63] = xdbl[(size_t)r0*64 + i];
  __syncthreads();
  if (t < 8) {
    float acc=0.f;
    #pragma unroll
    for (int s=0;s<16;s++) acc = fmaf(s_dbl[t][32+s], s_dbl[t][48+s], acc);
    s_bc[t] = acc;
  }
  __syncthreads();

  #pragma unroll
  for (int c=0;c<4;c++) {
    const int j = t + c*256;
    float w[32];
    {
      const short8* wp = (const short8*)(Wdt_t + (size_t)j*32);
      #pragma unroll
      for (int q=0;q<4;q++){
        short8 v = wp[q];
        #pragma unroll
        for (int e=0;e<8;e++) w[q*8+e] = b2f((unsigned short)v[e]);
      }
    }
    const float bj = bdt[j], dpj = Dp[j];
    #pragma unroll
    for (int rr=0;rr<8;rr++) {
      float acc = bj;
      #pragma unroll
      for (int k=0;k<32;k++) acc = fmaf(s_dbl[rr][k], w[k], acc);
      float dtv = softplusf(acc);
      float xv = b2f(xs[(size_t)(r0+rr)*1024 + j]);
      float yv = xv * fmaf(dtv, s_bc[rr], dpj);
      float zv = b2f(zs[(size_t)(r0+rr)*1024 + j]);
      xs[(size_t)(r0+rr)*1024 + j] = f2b(yv * zv);
    }
  }
}

extern "C" void kernel_launch(void* const* d_in, const int* in_sizes, int n_in,
                              void* d_out, int out_size, void* d_ws, size_t ws_size,
                              hipStream_t stream) {
  const float* obs       = (const float*)d_in[0];
  const float* comm_in   = (const float*)d_in[1];
  const float* conv_w    = (const float*)d_in[2];
  const float* conv_b    = (const float*)d_in[3];
  const float* enc_w     = (const float*)d_in[4];
  const float* enc_b     = (const float*)d_in[5];
  const float* proj_w    = (const float*)d_in[6];
  const float* proj_b    = (const float*)d_in[7];
  const float* norm_w    = (const float*)d_in[8];
  const float* in_proj_w = (const float*)d_in[9];
  const float* conv1d_w  = (const float*)d_in[10];
  const float* conv1d_b  = (const float*)d_in[11];
  const float* x_proj_w  = (const float*)d_in[12];
  const float* dt_proj_w = (const float*)d_in[13];
  const float* dt_proj_b = (const float*)d_in[14];
  // d_in[15] = A_log: dead at L=1
  const float* D_param   = (const float*)d_in[16];
  const float* out_proj_w= (const float*)d_in[17];
  const float* final_nw  = (const float*)d_in[18];
  const float* act_w     = (const float*)d_in[19];
  const float* act_b     = (const float*)d_in[20];
  const float* comm_w    = (const float*)d_in[21];
  const float* comm_b    = (const float*)d_in[22];
  const float* val_w     = (const float*)d_in[23];
  const float* val_b     = (const float*)d_in[24];
  float* out = (float*)d_out;

  char* W = (char*)d_ws;
  float* h             = (float*)W;                               // 16 MB
  unsigned short* u_b  = (unsigned short*)(W + (16u<<20));        //  8 MB
  unsigned short* xs_b = (unsigned short*)(W + (24u<<20));        // 16 MB (reused as g; v_b during frontend)
  unsigned short* zs_b = (unsigned short*)(W + (40u<<20));        // 16 MB (cat_b during frontend)
  unsigned short* wi_t = (unsigned short*)(W + (56u<<20));        //  4 MB (2 layers, [2048][512])
  unsigned short* wo_t = (unsigned short*)(W + (60u<<20));        //  2 MB (2 layers, [512][1024])
  float* xdbl          = (float*)(W + (62u<<20));                 //  2 MB [8192][64]
  unsigned short* wx_t = (unsigned short*)(W + (64u<<20));        // 256 KB (2 layers, [64][1024])
  unsigned short* wdt_t= (unsigned short*)(W + (64u<<20) + (256u<<10)); // 128 KB
  unsigned short* wh_t = (unsigned short*)(W + (65u<<20));        // 256 KB [256][512]
  unsigned short* we_t = (unsigned short*)(W + (65u<<20) + (512u<<10)); // 160 KB [256][320]
  unsigned short* wp_t = (unsigned short*)(W + (66u<<20));        // 384 KB [512][384]

  unsigned short* v_b   = xs_b;  // [8192][320] bf16, frontend only
  unsigned short* cat_b = zs_b;  // [8192][384] bf16, frontend only

  // per-launch weight transpose-converts (fp32 [K][N] -> bf16 [N][K])
  k_wt<<<dim3(16,64),256,0,stream>>>(in_proj_w,              wi_t,             512, 2048);
  k_wt<<<dim3(16,64),256,0,stream>>>(in_proj_w + 512*2048,   wi_t + 2048*512,  512, 2048);
  k_wt<<<dim3(32,16),256,0,stream>>>(out_proj_w,             wo_t,            1024,  512);
  k_wt<<<dim3(32,16),256,0,stream>>>(out_proj_w + 1024*512,  wo_t + 512*1024, 1024,  512);
  k_wt<<<dim3(32,2),256,0,stream>>>(x_proj_w,                wx_t,            1024,   64);
  k_wt<<<dim3(32,2),256,0,stream>>>(x_proj_w + 1024*64,      wx_t + 64*1024,  1024,   64);
  k_wt<<<dim3(1,32),256,0,stream>>>(dt_proj_w,               wdt_t,             32, 1024);
  k_wt<<<dim3(1,32),256,0,stream>>>(dt_proj_w + 32*1024,     wdt_t + 1024*32,   32, 1024);
  k_wt_heads<<<256,256,0,stream>>>(act_w, comm_w, val_w, wh_t);
  k_wt_pad<<<dim3(10,8),256,0,stream>>>(enc_w,  we_t, 288, 256, 320);
  k_wt<<<dim3(12,16),256,0,stream>>>(proj_w,    wp_t, 384, 512);

  // frontend
  k_front_prep<<<1024,256,0,stream>>>(obs, comm_in, conv_w, conv_b, v_b, cat_b);
  k_gemm_enc<<<dim3(64,2),256,0,stream>>>(v_b, we_t, enc_b, cat_b);
  k_gemm_proj<<<dim3(64,4),256,0,stream>>>(cat_b, wp_t, proj_b, h);

  for (int L=0; L<2; L++) {
    k_rms<<<2048,256,0,stream>>>(h, norm_w + L*512, u_b);
    k_gemm_inproj<<<dim3(64,16),256,0,stream>>>(u_b, wi_t + (size_t)L*2048*512,
                                                conv1d_w + L*1024*4, conv1d_b + L*1024, xs_b, zs_b);
    k_xdbl<<<64,256,0,stream>>>(xs_b, wx_t + (size_t)L*64*1024, xdbl);
    k_ssm2<<<1024,256,0,stream>>>(xs_b, zs_b, xdbl, wdt_t + (size_t)L*1024*32,
                                  dt_proj_b + L*1024, D_param + L*1024);
    k_gemm_outproj<<<dim3(64,4),256,0,stream>>>(xs_b, wo_t + (size_t)L*512*1024, h);
  }
  k_rms<<<2048,256,0,stream>>>(h, final_nw, u_b);
  k_gemm_heads<<<dim3(64,2),256,0,stream>>>(u_b, wh_t, act_b, comm_b, val_b, out);
}

// Round 5
// 279.392 us; speedup vs baseline: 4.5044x; 1.2381x over previous
//
#include <hip/hip_runtime.h>
#include <math.h>

// SymNet fused model. L=1 collapses the mamba block to:
//   u = rmsnorm(h); xz = u@Wi; x = silu(xz[:,:1024]*cw[:,3]+cb); z' = silu(xz[:,1024:])
//   xdbl = x@Wx; dt = softplus(xdbl[:,:32]@Wdt + bdt); bc = dot(xdbl[:,32:48], xdbl[:,48:64])
//   g = x*(dt*bc + D) * z'; h += g@Wo
// A_log (dA) is dead code: dA multiplies h0 == 0.
// R5: k_ssm2 replaced by MFMA k_dtgate (dt GEMM K=32 + fused gate, fast softplus);
//     all weight-prep launches merged into one k_wt_all.

typedef __bf16 bf16x8 __attribute__((ext_vector_type(8)));
typedef float f32x4 __attribute__((ext_vector_type(4)));
typedef short short8 __attribute__((ext_vector_type(8)));

__device__ __forceinline__ float siluf(float v){ return v / (1.f + __expf(-v)); }
__device__ __forceinline__ float spfast(float v){ return v > 15.f ? v : __logf(1.f + __expf(v)); }
__device__ __forceinline__ float b2f(unsigned short u){ return __uint_as_float(((unsigned)u)<<16); }
__device__ __forceinline__ unsigned short f2b(float f){
  unsigned u = __float_as_uint(f);
  return (unsigned short)((u + 0x7fffu + ((u>>16)&1u)) >> 16);
}
__device__ __forceinline__ void g2l16(const void* g, void* l){
  __builtin_amdgcn_global_load_lds((const __attribute__((address_space(1))) unsigned int*)g,
                                   (__attribute__((address_space(3))) unsigned int*)l, 16, 0, 0);
}

// ---------------- merged weight prep: all transposes + heads concat in ONE launch ----------------
__global__ __launch_bounds__(256) void k_wt_all(
    const float* __restrict__ in_proj_w, const float* __restrict__ out_proj_w,
    const float* __restrict__ x_proj_w,  const float* __restrict__ dt_proj_w,
    const float* __restrict__ enc_w,     const float* __restrict__ proj_w,
    const float* __restrict__ act_w, const float* __restrict__ comm_w, const float* __restrict__ val_w,
    unsigned short* __restrict__ wi_t, unsigned short* __restrict__ wo_t,
    unsigned short* __restrict__ wx_t, unsigned short* __restrict__ wdt_t,
    unsigned short* __restrict__ we_t, unsigned short* __restrict__ wp_t,
    unsigned short* __restrict__ wh_t)
{
  int b = blockIdx.x;
  // heads segment (last 256 blocks): Wh_t[256][512]; rows 0..3 act, 4..131 comm, 132 val, rest 0
  if (b >= 3536) {
    const int n = b - 3536;
    for (int k = threadIdx.x; k < 512; k += 256) {
      float v;
      if (n < 4)         v = act_w[k*4 + n];
      else if (n < 132)  v = comm_w[k*128 + (n-4)];
      else if (n == 132) v = val_w[k];
      else               v = 0.f;
      wh_t[(size_t)n*512 + k] = f2b(v);
    }
    return;
  }
  const float* Wsrc; unsigned short* Wdst; int Kd, Nd, KP, nkb;
  if (b < 2048) {        // in_proj, 2 layers: [512][2048] -> [2048][512]
    const int L = b >> 10; b &= 1023;
    Wsrc = in_proj_w + (size_t)L*512*2048; Wdst = wi_t + (size_t)L*2048*512;
    Kd = 512; Nd = 2048; KP = 512; nkb = 16;
  } else if (b < 3072) { // out_proj, 2 layers: [1024][512] -> [512][1024]
    b -= 2048; const int L = b >> 9; b &= 511;
    Wsrc = out_proj_w + (size_t)L*1024*512; Wdst = wo_t + (size_t)L*512*1024;
    Kd = 1024; Nd = 512; KP = 1024; nkb = 32;
  } else if (b < 3200) { // x_proj, 2 layers: [1024][64] -> [64][1024]
    b -= 3072; const int L = b >> 6; b &= 63;
    Wsrc = x_proj_w + (size_t)L*1024*64; Wdst = wx_t + (size_t)L*64*1024;
    Kd = 1024; Nd = 64; KP = 1024; nkb = 32;
  } else if (b < 3264) { // dt_proj, 2 layers: [32][1024] -> [1024][32]
    b -= 3200; const int L = b >> 5; b &= 31;
    Wsrc = dt_proj_w + (size_t)L*32*1024; Wdst = wdt_t + (size_t)L*1024*32;
    Kd = 32; Nd = 1024; KP = 32; nkb = 1;
  } else if (b < 3344) { // enc: [288][256] -> [256][320] (K padded)
    b -= 3264; Wsrc = enc_w; Wdst = we_t; Kd = 288; Nd = 256; KP = 320; nkb = 10;
  } else {               // proj: [384][512] -> [512][384]
    b -= 3344; Wsrc = proj_w; Wdst = wp_t; Kd = 384; Nd = 512; KP = 384; nkb = 12;
  }
  __shared__ float s[32][33];
  const int kb = (b % nkb)*32, nb = (b / nkb)*32;
  const int c = threadIdx.x & 31, r = threadIdx.x >> 5;
  #pragma unroll
  for (int i=0;i<32;i+=8) {
    const int k = kb + r + i;
    s[r+i][c] = (k < Kd) ? Wsrc[(size_t)k*Nd + nb + c] : 0.f;
  }
  __syncthreads();
  #pragma unroll
  for (int i=0;i<32;i+=8) Wdst[(size_t)(nb+r+i)*KP + kb + c] = f2b(s[c][r+i]);
}

// ---------------- rmsnorm -> bf16 (one row per wave) ----------------
__global__ __launch_bounds__(256) void k_rms(const float* __restrict__ h,
                                             const float* __restrict__ nw,
                                             unsigned short* __restrict__ u)
{
  const int l = threadIdx.x & 63;
  const size_t row = (size_t)blockIdx.x*4 + (threadIdx.x>>6);
  const float4* hp = (const float4*)(h + row*512) + l*2;
  float4 v0 = hp[0], v1 = hp[1];
  float ss = v0.x*v0.x+v0.y*v0.y+v0.z*v0.z+v0.w*v0.w
           + v1.x*v1.x+v1.y*v1.y+v1.z*v1.z+v1.w*v1.w;
  #pragma unroll
  for (int m=32;m;m>>=1) ss += __shfl_xor(ss, m, 64);
  const float sc = rsqrtf(ss*(1.f/512.f) + 1e-5f);
  const float4* np = (const float4*)nw + l*2;
  float4 w0 = np[0], w1 = np[1];
  short8 o;
  o[0]=(short)f2b(v0.x*sc*w0.x); o[1]=(short)f2b(v0.y*sc*w0.y);
  o[2]=(short)f2b(v0.z*sc*w0.z); o[3]=(short)f2b(v0.w*sc*w0.w);
  o[4]=(short)f2b(v1.x*sc*w1.x); o[5]=(short)f2b(v1.y*sc*w1.y);
  o[6]=(short)f2b(v1.z*sc*w1.z); o[7]=(short)f2b(v1.w*sc*w1.w);
  *(short8*)(u + row*512 + l*8) = o;
}

// ---------------- MFMA 128x128 tile mainloop (A [M][K] bf16, Bt [N][K] bf16) ----------------
template<int K>
__device__ __forceinline__ void gemm128(const unsigned short* __restrict__ A,
                                        const unsigned short* __restrict__ Bt,
                                        int r0, int c0,
                                        unsigned short* sA, unsigned short* sB,
                                        f32x4 acc[4][4])
{
  const int tid = threadIdx.x;
  const int l = tid & 63;
  const int wr = (tid>>7)&1, wc = (tid>>6)&1;
  const int rowA = tid>>3, kc8 = (tid&7)*8;
  const unsigned short* gA = A  + (size_t)(r0+rowA)*K + kc8;
  const unsigned short* gB = Bt + (size_t)(c0+rowA)*K + kc8;
  const int aOff = (wr*64 + (l&15))*64 + ((l>>4)*8);
  const int bOff = (wc*64 + (l&15))*64 + ((l>>4)*8);
  for (int kt=0; kt<K; kt+=64) {
    #pragma unroll
    for (int it=0; it<4; ++it) {
      g2l16(gA + (size_t)(it*32)*K + kt, sA + ((it*256+tid)*8));
      g2l16(gB + (size_t)(it*32)*K + kt, sB + ((it*256+tid)*8));
    }
    __syncthreads();
    #pragma unroll
    for (int ks=0; ks<64; ks+=32) {
      bf16x8 af[4], bfm[4];
      #pragma unroll
      for (int m=0;m<4;m++) af[m]  = *(const bf16x8*)(sA + (m*16)*64 + aOff + ks);
      #pragma unroll
      for (int n=0;n<4;n++) bfm[n] = *(const bf16x8*)(sB + (n*16)*64 + bOff + ks);
      #pragma unroll
      for (int m=0;m<4;m++)
        #pragma unroll
        for (int n=0;n<4;n++)
          acc[m][n] = __builtin_amdgcn_mfma_f32_16x16x32_bf16(af[m], bfm[n], acc[m][n], 0, 0, 0);
    }
    __syncthreads();
  }
}

// ---------------- in_proj: u_b(8192x512) @ Wi -> silu/conv-collapse -> xs,zs bf16 ----------------
__global__ __launch_bounds__(256) void k_gemm_inproj(
    const unsigned short* __restrict__ A, const unsigned short* __restrict__ Bt,
    const float* __restrict__ cw, const float* __restrict__ cb,
    unsigned short* __restrict__ xs, unsigned short* __restrict__ zs)
{
  __shared__ unsigned short sA[128*64], sB[128*64];
  f32x4 acc[4][4];
  #pragma unroll
  for (int m=0;m<4;m++)
    #pragma unroll
    for (int n=0;n<4;n++) acc[m][n] = (f32x4){0.f,0.f,0.f,0.f};
  const int r0 = blockIdx.x*128, c0 = blockIdx.y*128;
  gemm128<512>(A, Bt, r0, c0, sA, sB, acc);

  const int tid = threadIdx.x, l = tid & 63;
  const int wr = (tid>>7)&1, wc = (tid>>6)&1;
  const int colB = c0 + wc*64 + (l&15);
  const int rowB = r0 + wr*64 + ((l>>4)*4);
  if (c0 < 1024) {
    #pragma unroll
    for (int n=0;n<4;n++){
      const int col = colB + n*16;
      const float cw3 = cw[col*4+3], cbv = cb[col];
      #pragma unroll
      for (int m=0;m<4;m++)
        #pragma unroll
        for (int j=0;j<4;j++){
          const int row = rowB + m*16 + j;
          xs[(size_t)row*1024 + col] = f2b(siluf(fmaf(acc[m][n][j], cw3, cbv)));
        }
    }
  } else {
    #pragma unroll
    for (int n=0;n<4;n++){
      const int col = colB + n*16 - 1024;
      #pragma unroll
      for (int m=0;m<4;m++)
        #pragma unroll
        for (int j=0;j<4;j++){
          const int row = rowB + m*16 + j;
          zs[(size_t)row*1024 + col] = f2b(siluf(acc[m][n][j]));
        }
    }
  }
}

// ---------------- out_proj: g(8192x1024) @ Wo -> h += ----------------
__global__ __launch_bounds__(256) void k_gemm_outproj(
    const unsigned short* __restrict__ A, const unsigned short* __restrict__ Bt,
    float* __restrict__ h)
{
  __shared__ unsigned short sA[128*64], sB[128*64];
  f32x4 acc[4][4];
  #pragma unroll
  for (int m=0;m<4;m++)
    #pragma unroll
    for (int n=0;n<4;n++) acc[m][n] = (f32x4){0.f,0.f,0.f,0.f};
  const int r0 = blockIdx.x*128, c0 = blockIdx.y*128;
  gemm128<1024>(A, Bt, r0, c0, sA, sB, acc);

  const int tid = threadIdx.x, l = tid & 63;
  const int wr = (tid>>7)&1, wc = (tid>>6)&1;
  const int colB = c0 + wc*64 + (l&15);
  const int rowB = r0 + wr*64 + ((l>>4)*4);
  #pragma unroll
  for (int n=0;n<4;n++){
    const int col = colB + n*16;
    #pragma unroll
    for (int m=0;m<4;m++)
      #pragma unroll
      for (int j=0;j<4;j++){
        const int row = rowB + m*16 + j;
        h[(size_t)row*512 + col] += acc[m][n][j];
      }
  }
}

// ---------------- frontend GEMM1: v(8192x320) @ enc_t^T -> relu -> cat[:, :256] ----------------
__global__ __launch_bounds__(256) void k_gemm_enc(
    const unsigned short* __restrict__ A, const unsigned short* __restrict__ Bt,
    const float* __restrict__ bias, unsigned short* __restrict__ cat)
{
  __shared__ unsigned short sA[128*64], sB[128*64];
  f32x4 acc[4][4];
  #pragma unroll
  for (int m=0;m<4;m++)
    #pragma unroll
    for (int n=0;n<4;n++) acc[m][n] = (f32x4){0.f,0.f,0.f,0.f};
  const int r0 = blockIdx.x*128, c0 = blockIdx.y*128;
  gemm128<320>(A, Bt, r0, c0, sA, sB, acc);

  const int tid = threadIdx.x, l = tid & 63;
  const int wr = (tid>>7)&1, wc = (tid>>6)&1;
  const int colB = c0 + wc*64 + (l&15);
  const int rowB = r0 + wr*64 + ((l>>4)*4);
  #pragma unroll
  for (int n=0;n<4;n++){
    const int col = colB + n*16;
    const float bv = bias[col];
    #pragma unroll
    for (int m=0;m<4;m++)
      #pragma unroll
      for (int j=0;j<4;j++){
        const size_t row = rowB + m*16 + j;
        cat[row*384 + col] = f2b(fmaxf(acc[m][n][j] + bv, 0.f));
      }
  }
}

// ---------------- frontend GEMM2: cat(8192x384) @ proj_t^T -> relu -> h fp32 ----------------
__global__ __launch_bounds__(256) void k_gemm_proj(
    const unsigned short* __restrict__ A, const unsigned short* __restrict__ Bt,
    const float* __restrict__ bias, float* __restrict__ h)
{
  __shared__ unsigned short sA[128*64], sB[128*64];
  f32x4 acc[4][4];
  #pragma unroll
  for (int m=0;m<4;m++)
    #pragma unroll
    for (int n=0;n<4;n++) acc[m][n] = (f32x4){0.f,0.f,0.f,0.f};
  const int r0 = blockIdx.x*128, c0 = blockIdx.y*128;
  gemm128<384>(A, Bt, r0, c0, sA, sB, acc);

  const int tid = threadIdx.x, l = tid & 63;
  const int wr = (tid>>7)&1, wc = (tid>>6)&1;
  const int colB = c0 + wc*64 + (l&15);
  const int rowB = r0 + wr*64 + ((l>>4)*4);
  #pragma unroll
  for (int n=0;n<4;n++){
    const int col = colB + n*16;
    const float bv = bias[col];
    #pragma unroll
    for (int m=0;m<4;m++)
      #pragma unroll
      for (int j=0;j<4;j++){
        const size_t row = rowB + m*16 + j;
        h[row*512 + col] = fmaxf(acc[m][n][j] + bv, 0.f);
      }
  }
}

// ---------------- frontend prep: conv2d -> v bf16 [8192][320] (pad 0), comm -> cat[:,256:384] ----------------
__global__ __launch_bounds__(256) void k_front_prep(
    const float* __restrict__ obs, const float* __restrict__ comm_in,
    const float* __restrict__ conv_w, const float* __restrict__ conv_b,
    unsigned short* __restrict__ v, unsigned short* __restrict__ cat)
{
  __shared__ float s_obs[8][76];
  const int t = threadIdx.x;
  const int r0 = blockIdx.x * 8;

  for (int i = t; i < 8*75; i += 256) s_obs[i/75][i%75] = obs[(size_t)(r0 + i/75)*75 + i%75];
  __syncthreads();

  for (int i = t; i < 8*288; i += 256) {
    int r = i / 288, o = i % 288;
    int c = o / 9, ij = o % 9, oi = ij/3, oj = ij%3;
    float acc = conv_b[c];
    #pragma unroll
    for (int ic=0; ic<3; ic++)
      #pragma unroll
      for (int ki=0; ki<3; ki++)
        #pragma unroll
        for (int kj=0; kj<3; kj++)
          acc = fmaf(s_obs[r][ic*25 + (oi+ki)*5 + (oj+kj)], conv_w[((c*3+ic)*3+ki)*3+kj], acc);
    v[(size_t)(r0+r)*320 + o] = f2b(fmaxf(acc, 0.f));
  }
  // zero pad cols 288..319 (8 rows x 32 cols = 256)
  v[(size_t)(r0 + (t>>5))*320 + 288 + (t&31)] = 0;
  // comm -> cat[:, 256:384]
  for (int i = t; i < 8*128; i += 256) {
    int r = i >> 7, c = i & 127;
    cat[(size_t)(r0+r)*384 + 256 + c] = f2b(comm_in[(size_t)(r0+r)*128 + c]);
  }
}

// ---------------- heads GEMM: u(8192x512) @ Wh_t^T -> act/tanh(comm)/val scatter ----------------
__global__ __launch_bounds__(256) void k_gemm_heads(
    const unsigned short* __restrict__ A, const unsigned short* __restrict__ Bt,
    const float* __restrict__ act_b, const float* __restrict__ comm_b,
    const float* __restrict__ val_b, float* __restrict__ out)
{
  __shared__ unsigned short sA[128*64], sB[128*64];
  f32x4 acc[4][4];
  #pragma unroll
  for (int m=0;m<4;m++)
    #pragma unroll
    for (int n=0;n<4;n++) acc[m][n] = (f32x4){0.f,0.f,0.f,0.f};
  const int r0 = blockIdx.x*128, c0 = blockIdx.y*128;
  gemm128<512>(A, Bt, r0, c0, sA, sB, acc);

  const int tid = threadIdx.x, l = tid & 63;
  const int wr = (tid>>7)&1, wc = (tid>>6)&1;
  const int colB = c0 + wc*64 + (l&15);
  const int rowB = r0 + wr*64 + ((l>>4)*4);
  #pragma unroll
  for (int n=0;n<4;n++){
    const int col = colB + n*16;
    if (col > 132) continue;
    #pragma unroll
    for (int m=0;m<4;m++)
      #pragma unroll
      for (int j=0;j<4;j++){
        const size_t row = rowB + m*16 + j;
        float v = acc[m][n][j];
        if (col < 4)        out[row*4 + col] = v + act_b[col];
        else if (col < 132) out[32768 + row*128 + (col-4)] = tanhf(v + comm_b[col-4]);
        else                out[1081344 + row] = v + val_b[0];
      }
  }
}

// ---------------- x_dbl GEMM: xs(8192x1024) @ Wx_t^T(64x1024) -> xdbl fp32 ----------------
__global__ __launch_bounds__(256) void k_xdbl(
    const unsigned short* __restrict__ A, const unsigned short* __restrict__ Bt,
    float* __restrict__ xdbl)
{
  __shared__ unsigned short sA[128*64], sB[64*64];
  f32x4 acc[2][4];
  #pragma unroll
  for (int m=0;m<2;m++)
    #pragma unroll
    for (int n=0;n<4;n++) acc[m][n] = (f32x4){0.f,0.f,0.f,0.f};
  const int tid = threadIdx.x, l = tid & 63, w = tid>>6;
  const int r0 = blockIdx.x*128;
  const int rowA = tid>>3, kc8 = (tid&7)*8;
  const unsigned short* gA = A  + (size_t)(r0+rowA)*1024 + kc8;
  const unsigned short* gB = Bt + (size_t)rowA*1024 + kc8;
  const int aOff = (w*32 + (l&15))*64 + ((l>>4)*8);
  const int bOff = ((l&15))*64 + ((l>>4)*8);
  for (int kt=0; kt<1024; kt+=64) {
    #pragma unroll
    for (int it=0; it<4; ++it) g2l16(gA + (size_t)(it*32)*1024 + kt, sA + (it*256+tid)*8);
    #pragma unroll
    for (int it=0; it<2; ++it) g2l16(gB + (size_t)(it*32)*1024 + kt, sB + (it*256+tid)*8);
    __syncthreads();
    #pragma unroll
    for (int ks=0; ks<64; ks+=32) {
      bf16x8 af[2], bfm[4];
      #pragma unroll
      for (int m=0;m<2;m++) af[m]  = *(const bf16x8*)(sA + (m*16)*64 + aOff + ks);
      #pragma unroll
      for (int n=0;n<4;n++) bfm[n] = *(const bf16x8*)(sB + (n*16)*64 + bOff + ks);
      #pragma unroll
      for (int m=0;m<2;m++)
        #pragma unroll
        for (int n=0;n<4;n++)
          acc[m][n] = __builtin_amdgcn_mfma_f32_16x16x32_bf16(af[m], bfm[n], acc[m][n], 0, 0, 0);
    }
    __syncthreads();
  }
  #pragma unroll
  for (int n=0;n<4;n++){
    const int col = n*16 + (l&15);
    #pragma unroll
    for (int m=0;m<2;m++)
      #pragma unroll
      for (int j=0;j<4;j++){
        const size_t row = r0 + w*32 + m*16 + (l>>4)*4 + j;
        xdbl[row*64 + col] = acc[m][n][j];
      }
  }
}

// ---------------- dt GEMM (K=32, MFMA) + bc + gate: g = x*(dt*bc+D)*z' -> xs in place ----------------
__global__ __launch_bounds__(256) void k_dtgate(
    unsigned short* __restrict__ xs, const unsigned short* __restrict__ zs,
    const float* __restrict__ xdbl, const unsigned short* __restrict__ Wdt_t,
    const float* __restrict__ bdt, const float* __restrict__ Dp)
{
  __shared__ unsigned short sA[128*32];   // xdbl[:, :32] as bf16
  __shared__ unsigned short sB[128*32];   // Wdt_t tile [128 cols][32]
  __shared__ float s_bc[128];
  const int tid = threadIdx.x, l = tid & 63;
  const int r0 = blockIdx.x*128, c0 = blockIdx.y*128;

  { // sA: rows r0..r0+127, k 0..31, fp32 -> bf16
    const int row = tid >> 1, kh = (tid & 1)*16;
    const float4* p = (const float4*)(xdbl + (size_t)(r0+row)*64 + kh);
    float4 a = p[0], b = p[1], c = p[2], d = p[3];
    short8 o0, o1;
    o0[0]=(short)f2b(a.x); o0[1]=(short)f2b(a.y); o0[2]=(short)f2b(a.z); o0[3]=(short)f2b(a.w);
    o0[4]=(short)f2b(b.x); o0[5]=(short)f2b(b.y); o0[6]=(short)f2b(b.z); o0[7]=(short)f2b(b.w);
    o1[0]=(short)f2b(c.x); o1[1]=(short)f2b(c.y); o1[2]=(short)f2b(c.z); o1[3]=(short)f2b(c.w);
    o1[4]=(short)f2b(d.x); o1[5]=(short)f2b(d.y); o1[6]=(short)f2b(d.z); o1[7]=(short)f2b(d.w);
    *(short8*)(sA + row*32 + kh)     = o0;
    *(short8*)(sA + row*32 + kh + 8) = o1;
  }
  { // sB: Wdt_t rows c0..c0+127
    const int nrow = tid >> 1, kh = (tid & 1)*16;
    const short8* wp = (const short8*)(Wdt_t + (size_t)(c0+nrow)*32 + kh);
    *(short8*)(sB + nrow*32 + kh)     = wp[0];
    *(short8*)(sB + nrow*32 + kh + 8) = wp[1];
  }
  if (tid < 128) { // bc[row] = dot(xdbl[row][32:48], xdbl[row][48:64])
    const float4* q = (const float4*)(xdbl + (size_t)(r0+tid)*64 + 32);
    float4 b0=q[0], b1=q[1], b2=q[2], b3=q[3];
    float4 c0v=q[4], c1=q[5], c2=q[6], c3=q[7];
    float acc = b0.x*c0v.x + b0.y*c0v.y + b0.z*c0v.z + b0.w*c0v.w
              + b1.x*c1.x + b1.y*c1.y + b1.z*c1.z + b1.w*c1.w
              + b2.x*c2.x + b2.y*c2.y + b2.z*c2.z + b2.w*c2.w
              + b3.x*c3.x + b3.y*c3.y + b3.z*c3.z + b3.w*c3.w;
    s_bc[tid] = acc;
  }
  __syncthreads();

  const int wr = (tid>>7)&1, wc = (tid>>6)&1;
  bf16x8 af[4], bfm[4];
  #pragma unroll
  for (int m=0;m<4;m++) af[m]  = *(const bf16x8*)(sA + (wr*64 + m*16 + (l&15))*32 + (l>>4)*8);
  #pragma unroll
  for (int n=0;n<4;n++) bfm[n] = *(const bf16x8*)(sB + (wc*64 + n*16 + (l&15))*32 + (l>>4)*8);
  f32x4 acc[4][4];
  #pragma unroll
  for (int m=0;m<4;m++)
    #pragma unroll
    for (int n=0;n<4;n++)
      acc[m][n] = __builtin_amdgcn_mfma_f32_16x16x32_bf16(af[m], bfm[n], (f32x4){0.f,0.f,0.f,0.f}, 0, 0, 0);

  #pragma unroll
  for (int n=0;n<4;n++){
    const int col = c0 + wc*64 + n*16 + (l&15);
    const float bj = bdt[col], dpj = Dp[col];
    #pragma unroll
    for (int m=0;m<4;m++){
      const int rloc = wr*64 + m*16 + (l>>4)*4;
      #pragma unroll
      for (int j=0;j<4;j++){
        const size_t row = r0 + rloc + j;
        const float dtv = spfast(acc[m][n][j] + bj);
        const float f = fmaf(dtv, s_bc[rloc + j], dpj);
        const float x = b2f(xs[row*1024 + col]);
        const float z = b2f(zs[row*1024 + col]);
        xs[row*1024 + col] = f2b(x * f * z);
      }
    }
  }
}

extern "C" void kernel_launch(void* const* d_in, const int* in_sizes, int n_in,
                              void* d_out, int out_size, void* d_ws, size_t ws_size,
                              hipStream_t stream) {
  const float* obs       = (const float*)d_in[0];
  const float* comm_in   = (const float*)d_in[1];
  const float* conv_w    = (const float*)d_in[2];
  const float* conv_b    = (const float*)d_in[3];
  const float* enc_w     = (const float*)d_in[4];
  const float* enc_b     = (const float*)d_in[5];
  const float* proj_w    = (const float*)d_in[6];
  const float* proj_b    = (const float*)d_in[7];
  const float* norm_w    = (const float*)d_in[8];
  const float* in_proj_w = (const float*)d_in[9];
  const float* conv1d_w  = (const float*)d_in[10];
  const float* conv1d_b  = (const float*)d_in[11];
  const float* x_proj_w  = (const float*)d_in[12];
  const float* dt_proj_w = (const float*)d_in[13];
  const float* dt_proj_b = (const float*)d_in[14];
  // d_in[15] = A_log: dead at L=1
  const float* D_param   = (const float*)d_in[16];
  const float* out_proj_w= (const float*)d_in[17];
  const float* final_nw  = (const float*)d_in[18];
  const float* act_w     = (const float*)d_in[19];
  const float* act_b     = (const float*)d_in[20];
  const float* comm_w    = (const float*)d_in[21];
  const float* comm_b    = (const float*)d_in[22];
  const float* val_w     = (const float*)d_in[23];
  const float* val_b     = (const float*)d_in[24];
  float* out = (float*)d_out;

  char* W = (char*)d_ws;
  float* h             = (float*)W;                               // 16 MB
  unsigned short* u_b  = (unsigned short*)(W + (16u<<20));        //  8 MB
  unsigned short* xs_b = (unsigned short*)(W + (24u<<20));        // 16 MB (reused as g; v_b during frontend)
  unsigned short* zs_b = (unsigned short*)(W + (40u<<20));        // 16 MB (cat_b during frontend)
  unsigned short* wi_t = (unsigned short*)(W + (56u<<20));        //  4 MB (2 layers, [2048][512])
  unsigned short* wo_t = (unsigned short*)(W + (60u<<20));        //  2 MB (2 layers, [512][1024])
  float* xdbl          = (float*)(W + (62u<<20));                 //  2 MB [8192][64]
  unsigned short* wx_t = (unsigned short*)(W + (64u<<20));        // 256 KB (2 layers, [64][1024])
  unsigned short* wdt_t= (unsigned short*)(W + (64u<<20) + (256u<<10)); // 128 KB
  unsigned short* wh_t = (unsigned short*)(W + (65u<<20));        // 256 KB [256][512]
  unsigned short* we_t = (unsigned short*)(W + (65u<<20) + (512u<<10)); // 160 KB [256][320]
  unsigned short* wp_t = (unsigned short*)(W + (66u<<20));        // 384 KB [512][384]

  unsigned short* v_b   = xs_b;  // [8192][320] bf16, frontend only
  unsigned short* cat_b = zs_b;  // [8192][384] bf16, frontend only

  // all weight preps in ONE launch
  k_wt_all<<<3792,256,0,stream>>>(in_proj_w, out_proj_w, x_proj_w, dt_proj_w,
                                  enc_w, proj_w, act_w, comm_w, val_w,
                                  wi_t, wo_t, wx_t, wdt_t, we_t, wp_t, wh_t);

  // frontend
  k_front_prep<<<1024,256,0,stream>>>(obs, comm_in, conv_w, conv_b, v_b, cat_b);
  k_gemm_enc<<<dim3(64,2),256,0,stream>>>(v_b, we_t, enc_b, cat_b);
  k_gemm_proj<<<dim3(64,4),256,0,stream>>>(cat_b, wp_t, proj_b, h);

  for (int L=0; L<2; L++) {
    k_rms<<<2048,256,0,stream>>>(h, norm_w + L*512, u_b);
    k_gemm_inproj<<<dim3(64,16),256,0,stream>>>(u_b, wi_t + (size_t)L*2048*512,
                                                conv1d_w + L*1024*4, conv1d_b + L*1024, xs_b, zs_b);
    k_xdbl<<<64,256,0,stream>>>(xs_b, wx_t + (size_t)L*64*1024, xdbl);
    k_dtgate<<<dim3(64,8),256,0,stream>>>(xs_b, zs_b, xdbl, wdt_t + (size_t)L*1024*32,
                                          dt_proj_b + L*1024, D_param + L*1024);
    k_gemm_outproj<<<dim3(64,4),256,0,stream>>>(xs_b, wo_t + (size_t)L*512*1024, h);
  }
  k_rms<<<2048,256,0,stream>>>(h, final_nw, u_b);
  k_gemm_heads<<<dim3(64,2),256,0,stream>>>(u_b, wh_t, act_b, comm_b, val_b, out);
}

// Round 6
// 253.674 us; speedup vs baseline: 4.9611x; 1.1014x over previous
//
#include <hip/hip_runtime.h>
#include <math.h>

// SymNet fused model. L=1 collapses the mamba block to:
//   u = rmsnorm(h); xz = u@Wi; x = silu(xz[:,:1024]*cw[:,3]+cb); z' = silu(xz[:,1024:])
//   xdbl = x@Wx; dt = softplus(xdbl[:,:32]@Wdt + bdt); bc = dot(xdbl[:,32:48], xdbl[:,48:64])
//   g = x*(dt*bc + D) * z'; h += g@Wo
// A_log (dA) is dead code: dA multiplies h0 == 0.
// R6: BN=64 GEMM variant for N-narrow GEMMs (outproj/proj/enc/heads -> 2x blocks);
//     k_xdbl2 at grid 256 emits bf16 dt_in + bc directly; front_prep merged into wt_all.

typedef __bf16 bf16x8 __attribute__((ext_vector_type(8)));
typedef float f32x4 __attribute__((ext_vector_type(4)));
typedef short short8 __attribute__((ext_vector_type(8)));
typedef short short4v __attribute__((ext_vector_type(4)));

__device__ __forceinline__ float siluf(float v){ return v / (1.f + __expf(-v)); }
__device__ __forceinline__ float spfast(float v){ return v > 15.f ? v : __logf(1.f + __expf(v)); }
__device__ __forceinline__ float b2f(unsigned short u){ return __uint_as_float(((unsigned)u)<<16); }
__device__ __forceinline__ unsigned short f2b(float f){
  unsigned u = __float_as_uint(f);
  return (unsigned short)((u + 0x7fffu + ((u>>16)&1u)) >> 16);
}
__device__ __forceinline__ void g2l16(const void* g, void* l){
  __builtin_amdgcn_global_load_lds((const __attribute__((address_space(1))) unsigned int*)g,
                                   (__attribute__((address_space(3))) unsigned int*)l, 16, 0, 0);
}

// ---------------- merged prep: all weight transposes + heads concat + frontend conv, ONE launch ----------------
__global__ __launch_bounds__(256) void k_wt_all(
    const float* __restrict__ in_proj_w, const float* __restrict__ out_proj_w,
    const float* __restrict__ x_proj_w,  const float* __restrict__ dt_proj_w,
    const float* __restrict__ enc_w,     const float* __restrict__ proj_w,
    const float* __restrict__ act_w, const float* __restrict__ comm_w, const float* __restrict__ val_w,
    const float* __restrict__ obs, const float* __restrict__ comm_in,
    const float* __restrict__ conv_w, const float* __restrict__ conv_b,
    unsigned short* __restrict__ wi_t, unsigned short* __restrict__ wo_t,
    unsigned short* __restrict__ wx_t, unsigned short* __restrict__ wdt_t,
    unsigned short* __restrict__ we_t, unsigned short* __restrict__ wp_t,
    unsigned short* __restrict__ wh_t,
    unsigned short* __restrict__ v, unsigned short* __restrict__ cat)
{
  int b = blockIdx.x;
  const int t = threadIdx.x;

  // frontend prep segment: blocks 3792..4815 (1024 blocks, 8 rows each)
  if (b >= 3792) {
    __shared__ float s_obs[8][76];
    const int r0 = (b - 3792) * 8;
    for (int i = t; i < 8*75; i += 256) s_obs[i/75][i%75] = obs[(size_t)(r0 + i/75)*75 + i%75];
    __syncthreads();
    for (int i = t; i < 8*288; i += 256) {
      int r = i / 288, o = i % 288;
      int c = o / 9, ij = o % 9, oi = ij/3, oj = ij%3;
      float acc = conv_b[c];
      #pragma unroll
      for (int ic=0; ic<3; ic++)
        #pragma unroll
        for (int ki=0; ki<3; ki++)
          #pragma unroll
          for (int kj=0; kj<3; kj++)
            acc = fmaf(s_obs[r][ic*25 + (oi+ki)*5 + (oj+kj)], conv_w[((c*3+ic)*3+ki)*3+kj], acc);
      v[(size_t)(r0+r)*320 + o] = f2b(fmaxf(acc, 0.f));
    }
    v[(size_t)(r0 + (t>>5))*320 + 288 + (t&31)] = 0;  // zero pad cols 288..319
    for (int i = t; i < 8*128; i += 256) {
      int r = i >> 7, c = i & 127;
      cat[(size_t)(r0+r)*384 + 256 + c] = f2b(comm_in[(size_t)(r0+r)*128 + c]);
    }
    return;
  }
  // heads concat segment: blocks 3536..3791
  if (b >= 3536) {
    const int n = b - 3536;
    for (int k = t; k < 512; k += 256) {
      float v2;
      if (n < 4)         v2 = act_w[k*4 + n];
      else if (n < 132)  v2 = comm_w[k*128 + (n-4)];
      else if (n == 132) v2 = val_w[k];
      else               v2 = 0.f;
      wh_t[(size_t)n*512 + k] = f2b(v2);
    }
    return;
  }
  const float* Wsrc; unsigned short* Wdst; int Kd, Nd, KP, nkb;
  if (b < 2048) {        // in_proj, 2 layers: [512][2048] -> [2048][512]
    const int L = b >> 10; b &= 1023;
    Wsrc = in_proj_w + (size_t)L*512*2048; Wdst = wi_t + (size_t)L*2048*512;
    Kd = 512; Nd = 2048; KP = 512; nkb = 16;
  } else if (b < 3072) { // out_proj, 2 layers: [1024][512] -> [512][1024]
    b -= 2048; const int L = b >> 9; b &= 511;
    Wsrc = out_proj_w + (size_t)L*1024*512; Wdst = wo_t + (size_t)L*512*1024;
    Kd = 1024; Nd = 512; KP = 1024; nkb = 32;
  } else if (b < 3200) { // x_proj, 2 layers: [1024][64] -> [64][1024]
    b -= 3072; const int L = b >> 6; b &= 63;
    Wsrc = x_proj_w + (size_t)L*1024*64; Wdst = wx_t + (size_t)L*64*1024;
    Kd = 1024; Nd = 64; KP = 1024; nkb = 32;
  } else if (b < 3264) { // dt_proj, 2 layers: [32][1024] -> [1024][32]
    b -= 3200; const int L = b >> 5; b &= 31;
    Wsrc = dt_proj_w + (size_t)L*32*1024; Wdst = wdt_t + (size_t)L*1024*32;
    Kd = 32; Nd = 1024; KP = 32; nkb = 1;
  } else if (b < 3344) { // enc: [288][256] -> [256][320] (K padded)
    b -= 3264; Wsrc = enc_w; Wdst = we_t; Kd = 288; Nd = 256; KP = 320; nkb = 10;
  } else {               // proj: [384][512] -> [512][384]
    b -= 3344; Wsrc = proj_w; Wdst = wp_t; Kd = 384; Nd = 512; KP = 384; nkb = 12;
  }
  __shared__ float s[32][33];
  const int kb = (b % nkb)*32, nb = (b / nkb)*32;
  const int c = t & 31, r = t >> 5;
  #pragma unroll
  for (int i=0;i<32;i+=8) {
    const int k = kb + r + i;
    s[r+i][c] = (k < Kd) ? Wsrc[(size_t)k*Nd + nb + c] : 0.f;
  }
  __syncthreads();
  #pragma unroll
  for (int i=0;i<32;i+=8) Wdst[(size_t)(nb+r+i)*KP + kb + c] = f2b(s[c][r+i]);
}

// ---------------- rmsnorm -> bf16 (one row per wave) ----------------
__global__ __launch_bounds__(256) void k_rms(const float* __restrict__ h,
                                             const float* __restrict__ nw,
                                             unsigned short* __restrict__ u)
{
  const int l = threadIdx.x & 63;
  const size_t row = (size_t)blockIdx.x*4 + (threadIdx.x>>6);
  const float4* hp = (const float4*)(h + row*512) + l*2;
  float4 v0 = hp[0], v1 = hp[1];
  float ss = v0.x*v0.x+v0.y*v0.y+v0.z*v0.z+v0.w*v0.w
           + v1.x*v1.x+v1.y*v1.y+v1.z*v1.z+v1.w*v1.w;
  #pragma unroll
  for (int m=32;m;m>>=1) ss += __shfl_xor(ss, m, 64);
  const float sc = rsqrtf(ss*(1.f/512.f) + 1e-5f);
  const float4* np = (const float4*)nw + l*2;
  float4 w0 = np[0], w1 = np[1];
  short8 o;
  o[0]=(short)f2b(v0.x*sc*w0.x); o[1]=(short)f2b(v0.y*sc*w0.y);
  o[2]=(short)f2b(v0.z*sc*w0.z); o[3]=(short)f2b(v0.w*sc*w0.w);
  o[4]=(short)f2b(v1.x*sc*w1.x); o[5]=(short)f2b(v1.y*sc*w1.y);
  o[6]=(short)f2b(v1.z*sc*w1.z); o[7]=(short)f2b(v1.w*sc*w1.w);
  *(short8*)(u + row*512 + l*8) = o;
}

// ---------------- MFMA 128xNB tile mainloop (A [M][K] bf16, Bt [N][K] bf16) ----------------
template<int K, int NB>
__device__ __forceinline__ void gemmT(const unsigned short* __restrict__ A,
                                      const unsigned short* __restrict__ Bt,
                                      int r0, int c0,
                                      unsigned short* sA, unsigned short* sB,
                                      f32x4 (&acc)[4][NB/32])
{
  constexpr int NF = NB/32;
  const int tid = threadIdx.x;
  const int l = tid & 63;
  const int wr = (tid>>7)&1, wc = (tid>>6)&1;
  const int rowA = tid>>3, kc8 = (tid&7)*8;
  const unsigned short* gA = A  + (size_t)(r0+rowA)*K + kc8;
  const unsigned short* gB = Bt + (size_t)(c0+rowA)*K + kc8;
  const int aOff = (wr*64 + (l&15))*64 + ((l>>4)*8);
  const int bOff = (wc*(NB/2) + (l&15))*64 + ((l>>4)*8);
  for (int kt=0; kt<K; kt+=64) {
    #pragma unroll
    for (int it=0; it<4; ++it) g2l16(gA + (size_t)(it*32)*K + kt, sA + ((it*256+tid)*8));
    #pragma unroll
    for (int it=0; it<NB/32; ++it) g2l16(gB + (size_t)(it*32)*K + kt, sB + ((it*256+tid)*8));
    __syncthreads();
    #pragma unroll
    for (int ks=0; ks<64; ks+=32) {
      bf16x8 af[4], bfm[NF];
      #pragma unroll
      for (int m=0;m<4;m++) af[m]  = *(const bf16x8*)(sA + (m*16)*64 + aOff + ks);
      #pragma unroll
      for (int n=0;n<NF;n++) bfm[n] = *(const bf16x8*)(sB + (n*16)*64 + bOff + ks);
      #pragma unroll
      for (int m=0;m<4;m++)
        #pragma unroll
        for (int n=0;n<NF;n++)
          acc[m][n] = __builtin_amdgcn_mfma_f32_16x16x32_bf16(af[m], bfm[n], acc[m][n], 0, 0, 0);
    }
    __syncthreads();
  }
}

// ---------------- in_proj: u_b(8192x512) @ Wi -> silu/conv-collapse -> xs,zs bf16 ----------------
__global__ __launch_bounds__(256) void k_gemm_inproj(
    const unsigned short* __restrict__ A, const unsigned short* __restrict__ Bt,
    const float* __restrict__ cw, const float* __restrict__ cb,
    unsigned short* __restrict__ xs, unsigned short* __restrict__ zs)
{
  __shared__ unsigned short sA[128*64], sB[128*64];
  f32x4 acc[4][4];
  #pragma unroll
  for (int m=0;m<4;m++)
    #pragma unroll
    for (int n=0;n<4;n++) acc[m][n] = (f32x4){0.f,0.f,0.f,0.f};
  const int r0 = blockIdx.x*128, c0 = blockIdx.y*128;
  gemmT<512,128>(A, Bt, r0, c0, sA, sB, acc);

  const int tid = threadIdx.x, l = tid & 63;
  const int wr = (tid>>7)&1, wc = (tid>>6)&1;
  const int colB = c0 + wc*64 + (l&15);
  const int rowB = r0 + wr*64 + ((l>>4)*4);
  if (c0 < 1024) {
    #pragma unroll
    for (int n=0;n<4;n++){
      const int col = colB + n*16;
      const float cw3 = cw[col*4+3], cbv = cb[col];
      #pragma unroll
      for (int m=0;m<4;m++)
        #pragma unroll
        for (int j=0;j<4;j++){
          const int row = rowB + m*16 + j;
          xs[(size_t)row*1024 + col] = f2b(siluf(fmaf(acc[m][n][j], cw3, cbv)));
        }
    }
  } else {
    #pragma unroll
    for (int n=0;n<4;n++){
      const int col = colB + n*16 - 1024;
      #pragma unroll
      for (int m=0;m<4;m++)
        #pragma unroll
        for (int j=0;j<4;j++){
          const int row = rowB + m*16 + j;
          zs[(size_t)row*1024 + col] = f2b(siluf(acc[m][n][j]));
        }
    }
  }
}

// ---------------- out_proj: g(8192x1024) @ Wo -> h += (BN=64, grid 64x8) ----------------
__global__ __launch_bounds__(256) void k_gemm_outproj(
    const unsigned short* __restrict__ A, const unsigned short* __restrict__ Bt,
    float* __restrict__ h)
{
  __shared__ unsigned short sA[128*64], sB[64*64];
  f32x4 acc[4][2];
  #pragma unroll
  for (int m=0;m<4;m++)
    #pragma unroll
    for (int n=0;n<2;n++) acc[m][n] = (f32x4){0.f,0.f,0.f,0.f};
  const int r0 = blockIdx.x*128, c0 = blockIdx.y*64;
  gemmT<1024,64>(A, Bt, r0, c0, sA, sB, acc);

  const int tid = threadIdx.x, l = tid & 63;
  const int wr = (tid>>7)&1, wc = (tid>>6)&1;
  const int colB = c0 + wc*32 + (l&15);
  const int rowB = r0 + wr*64 + ((l>>4)*4);
  #pragma unroll
  for (int n=0;n<2;n++){
    const int col = colB + n*16;
    #pragma unroll
    for (int m=0;m<4;m++)
      #pragma unroll
      for (int j=0;j<4;j++){
        const int row = rowB + m*16 + j;
        h[(size_t)row*512 + col] += acc[m][n][j];
      }
  }
}

// ---------------- frontend GEMM1: v(8192x320) @ enc_t^T -> relu -> cat[:, :256] (BN=64) ----------------
__global__ __launch_bounds__(256) void k_gemm_enc(
    const unsigned short* __restrict__ A, const unsigned short* __restrict__ Bt,
    const float* __restrict__ bias, unsigned short* __restrict__ cat)
{
  __shared__ unsigned short sA[128*64], sB[64*64];
  f32x4 acc[4][2];
  #pragma unroll
  for (int m=0;m<4;m++)
    #pragma unroll
    for (int n=0;n<2;n++) acc[m][n] = (f32x4){0.f,0.f,0.f,0.f};
  const int r0 = blockIdx.x*128, c0 = blockIdx.y*64;
  gemmT<320,64>(A, Bt, r0, c0, sA, sB, acc);

  const int tid = threadIdx.x, l = tid & 63;
  const int wr = (tid>>7)&1, wc = (tid>>6)&1;
  const int colB = c0 + wc*32 + (l&15);
  const int rowB = r0 + wr*64 + ((l>>4)*4);
  #pragma unroll
  for (int n=0;n<2;n++){
    const int col = colB + n*16;
    const float bv = bias[col];
    #pragma unroll
    for (int m=0;m<4;m++)
      #pragma unroll
      for (int j=0;j<4;j++){
        const size_t row = rowB + m*16 + j;
        cat[row*384 + col] = f2b(fmaxf(acc[m][n][j] + bv, 0.f));
      }
  }
}

// ---------------- frontend GEMM2: cat(8192x384) @ proj_t^T -> relu -> h fp32 (BN=64) ----------------
__global__ __launch_bounds__(256) void k_gemm_proj(
    const unsigned short* __restrict__ A, const unsigned short* __restrict__ Bt,
    const float* __restrict__ bias, float* __restrict__ h)
{
  __shared__ unsigned short sA[128*64], sB[64*64];
  f32x4 acc[4][2];
  #pragma unroll
  for (int m=0;m<4;m++)
    #pragma unroll
    for (int n=0;n<2;n++) acc[m][n] = (f32x4){0.f,0.f,0.f,0.f};
  const int r0 = blockIdx.x*128, c0 = blockIdx.y*64;
  gemmT<384,64>(A, Bt, r0, c0, sA, sB, acc);

  const int tid = threadIdx.x, l = tid & 63;
  const int wr = (tid>>7)&1, wc = (tid>>6)&1;
  const int colB = c0 + wc*32 + (l&15);
  const int rowB = r0 + wr*64 + ((l>>4)*4);
  #pragma unroll
  for (int n=0;n<2;n++){
    const int col = colB + n*16;
    const float bv = bias[col];
    #pragma unroll
    for (int m=0;m<4;m++)
      #pragma unroll
      for (int j=0;j<4;j++){
        const size_t row = rowB + m*16 + j;
        h[row*512 + col] = fmaxf(acc[m][n][j] + bv, 0.f);
      }
  }
}

// ---------------- heads GEMM: u(8192x512) @ Wh_t^T -> act/tanh(comm)/val scatter (BN=64) ----------------
__global__ __launch_bounds__(256) void k_gemm_heads(
    const unsigned short* __restrict__ A, const unsigned short* __restrict__ Bt,
    const float* __restrict__ act_b, const float* __restrict__ comm_b,
    const float* __restrict__ val_b, float* __restrict__ out)
{
  __shared__ unsigned short sA[128*64], sB[64*64];
  f32x4 acc[4][2];
  #pragma unroll
  for (int m=0;m<4;m++)
    #pragma unroll
    for (int n=0;n<2;n++) acc[m][n] = (f32x4){0.f,0.f,0.f,0.f};
  const int r0 = blockIdx.x*128, c0 = blockIdx.y*64;
  gemmT<512,64>(A, Bt, r0, c0, sA, sB, acc);

  const int tid = threadIdx.x, l = tid & 63;
  const int wr = (tid>>7)&1, wc = (tid>>6)&1;
  const int colB = c0 + wc*32 + (l&15);
  const int rowB = r0 + wr*64 + ((l>>4)*4);
  #pragma unroll
  for (int n=0;n<2;n++){
    const int col = colB + n*16;
    if (col > 132) continue;
    #pragma unroll
    for (int m=0;m<4;m++)
      #pragma unroll
      for (int j=0;j<4;j++){
        const size_t row = rowB + m*16 + j;
        float v = acc[m][n][j];
        if (col < 4)        out[row*4 + col] = v + act_b[col];
        else if (col < 132) out[32768 + row*128 + (col-4)] = tanhf(v + comm_b[col-4]);
        else                out[1081344 + row] = v + val_b[0];
      }
  }
}

// ---------------- x_dbl GEMM v2: xs(8192x1024) @ Wx_t^T -> dt_in bf16 [8192][32] + bc f32 ----------------
// M-tile 32, grid 256 (all CUs), BK=128. Wave w owns output cols w*16..w*16+15.
__global__ __launch_bounds__(256) void k_xdbl2(
    const unsigned short* __restrict__ xs, const unsigned short* __restrict__ Wx_t,
    unsigned short* __restrict__ dt_in, float* __restrict__ bc_g)
{
  __shared__ unsigned short sA[32*128];   // 8KB
  __shared__ unsigned short sB[64*128];   // 16KB
  __shared__ float s_dbl[32][64];         // 8KB
  const int tid = threadIdx.x, l = tid & 63, w = tid >> 6;
  const int r0 = blockIdx.x * 32;
  f32x4 acc0 = (f32x4){0.f,0.f,0.f,0.f}, acc1 = (f32x4){0.f,0.f,0.f,0.f};
  for (int kt = 0; kt < 1024; kt += 128) {
    #pragma unroll
    for (int it=0; it<2; ++it) {  // A: 32 rows x 128 k
      const int idx = it*256 + tid;
      g2l16(xs + (size_t)(r0 + (idx>>4))*1024 + (idx&15)*8 + kt, sA + idx*8);
    }
    #pragma unroll
    for (int it=0; it<4; ++it) {  // B: 64 rows x 128 k
      const int idx = it*256 + tid;
      g2l16(Wx_t + (size_t)(idx>>4)*1024 + (idx&15)*8 + kt, sB + idx*8);
    }
    __syncthreads();
    #pragma unroll
    for (int ks=0; ks<128; ks+=32) {
      bf16x8 a0 = *(const bf16x8*)(sA + ((l&15))*128      + (l>>4)*8 + ks);
      bf16x8 a1 = *(const bf16x8*)(sA + (16+(l&15))*128   + (l>>4)*8 + ks);
      bf16x8 bf = *(const bf16x8*)(sB + (w*16+(l&15))*128 + (l>>4)*8 + ks);
      acc0 = __builtin_amdgcn_mfma_f32_16x16x32_bf16(a0, bf, acc0, 0, 0, 0);
      acc1 = __builtin_amdgcn_mfma_f32_16x16x32_bf16(a1, bf, acc1, 0, 0, 0);
    }
    __syncthreads();
  }
  #pragma unroll
  for (int j=0;j<4;j++) {
    s_dbl[(l>>4)*4 + j]     [w*16 + (l&15)] = acc0[j];
    s_dbl[16 + (l>>4)*4 + j][w*16 + (l&15)] = acc1[j];
  }
  __syncthreads();
  if (tid < 32) {
    float a = 0.f;
    #pragma unroll
    for (int s=0;s<16;s++) a = fmaf(s_dbl[tid][32+s], s_dbl[tid][48+s], a);
    bc_g[r0 + tid] = a;
  }
  { // dt_in: 32 rows x 32 cols bf16
    const int r = tid >> 3, c4 = (tid & 7)*4;
    short4v o;
    o[0] = (short)f2b(s_dbl[r][c4]);   o[1] = (short)f2b(s_dbl[r][c4+1]);
    o[2] = (short)f2b(s_dbl[r][c4+2]); o[3] = (short)f2b(s_dbl[r][c4+3]);
    *(short4v*)(dt_in + (size_t)(r0+r)*32 + c4) = o;
  }
}

// ---------------- dt GEMM (K=32, MFMA) + gate: g = x*(dt*bc+D)*z' -> xs in place ----------------
__global__ __launch_bounds__(256) void k_dtgate2(
    unsigned short* __restrict__ xs, const unsigned short* __restrict__ zs,
    const unsigned short* __restrict__ dt_in, const float* __restrict__ bc_g,
    const unsigned short* __restrict__ Wdt_t,
    const float* __restrict__ bdt, const float* __restrict__ Dp)
{
  __shared__ unsigned short sA[128*32];   // dt_in rows
  __shared__ unsigned short sB[128*32];   // Wdt_t tile [128 cols][32]
  __shared__ float s_bc[128];
  const int tid = threadIdx.x, l = tid & 63;
  const int r0 = blockIdx.x*128, c0 = blockIdx.y*128;

  { const int row = tid >> 1, kh = (tid & 1)*16;
    const short8* ap = (const short8*)(dt_in + (size_t)(r0+row)*32 + kh);
    *(short8*)(sA + row*32 + kh)     = ap[0];
    *(short8*)(sA + row*32 + kh + 8) = ap[1];
    const short8* wp = (const short8*)(Wdt_t + (size_t)(c0+row)*32 + kh);
    *(short8*)(sB + row*32 + kh)     = wp[0];
    *(short8*)(sB + row*32 + kh + 8) = wp[1];
  }
  if (tid < 128) s_bc[tid] = bc_g[r0 + tid];
  __syncthreads();

  const int wr = (tid>>7)&1, wc = (tid>>6)&1;
  bf16x8 af[4], bfm[4];
  #pragma unroll
  for (int m=0;m<4;m++) af[m]  = *(const bf16x8*)(sA + (wr*64 + m*16 + (l&15))*32 + (l>>4)*8);
  #pragma unroll
  for (int n=0;n<4;n++) bfm[n] = *(const bf16x8*)(sB + (wc*64 + n*16 + (l&15))*32 + (l>>4)*8);
  f32x4 acc[4][4];
  #pragma unroll
  for (int m=0;m<4;m++)
    #pragma unroll
    for (int n=0;n<4;n++)
      acc[m][n] = __builtin_amdgcn_mfma_f32_16x16x32_bf16(af[m], bfm[n], (f32x4){0.f,0.f,0.f,0.f}, 0, 0, 0);

  #pragma unroll
  for (int n=0;n<4;n++){
    const int col = c0 + wc*64 + n*16 + (l&15);
    const float bj = bdt[col], dpj = Dp[col];
    #pragma unroll
    for (int m=0;m<4;m++){
      const int rloc = wr*64 + m*16 + (l>>4)*4;
      #pragma unroll
      for (int j=0;j<4;j++){
        const size_t row = r0 + rloc + j;
        const float dtv = spfast(acc[m][n][j] + bj);
        const float f = fmaf(dtv, s_bc[rloc + j], dpj);
        const float x = b2f(xs[row*1024 + col]);
        const float z = b2f(zs[row*1024 + col]);
        xs[row*1024 + col] = f2b(x * f * z);
      }
    }
  }
}

extern "C" void kernel_launch(void* const* d_in, const int* in_sizes, int n_in,
                              void* d_out, int out_size, void* d_ws, size_t ws_size,
                              hipStream_t stream) {
  const float* obs       = (const float*)d_in[0];
  const float* comm_in   = (const float*)d_in[1];
  const float* conv_w    = (const float*)d_in[2];
  const float* conv_b    = (const float*)d_in[3];
  const float* enc_w     = (const float*)d_in[4];
  const float* enc_b     = (const float*)d_in[5];
  const float* proj_w    = (const float*)d_in[6];
  const float* proj_b    = (const float*)d_in[7];
  const float* norm_w    = (const float*)d_in[8];
  const float* in_proj_w = (const float*)d_in[9];
  const float* conv1d_w  = (const float*)d_in[10];
  const float* conv1d_b  = (const float*)d_in[11];
  const float* x_proj_w  = (const float*)d_in[12];
  const float* dt_proj_w = (const float*)d_in[13];
  const float* dt_proj_b = (const float*)d_in[14];
  // d_in[15] = A_log: dead at L=1
  const float* D_param   = (const float*)d_in[16];
  const float* out_proj_w= (const float*)d_in[17];
  const float* final_nw  = (const float*)d_in[18];
  const float* act_w     = (const float*)d_in[19];
  const float* act_b     = (const float*)d_in[20];
  const float* comm_w    = (const float*)d_in[21];
  const float* comm_b    = (const float*)d_in[22];
  const float* val_w     = (const float*)d_in[23];
  const float* val_b     = (const float*)d_in[24];
  float* out = (float*)d_out;

  char* W = (char*)d_ws;
  float* h             = (float*)W;                               // 16 MB
  unsigned short* u_b  = (unsigned short*)(W + (16u<<20));        //  8 MB
  unsigned short* xs_b = (unsigned short*)(W + (24u<<20));        // 16 MB (reused as g; v_b during frontend)
  unsigned short* zs_b = (unsigned short*)(W + (40u<<20));        // 16 MB (cat_b during frontend)
  unsigned short* wi_t = (unsigned short*)(W + (56u<<20));        //  4 MB (2 layers, [2048][512])
  unsigned short* wo_t = (unsigned short*)(W + (60u<<20));        //  2 MB (2 layers, [512][1024])
  unsigned short* dt_in= (unsigned short*)(W + (62u<<20));        // 512 KB [8192][32]
  float* bc_g          = (float*)(W + (62u<<20) + (512u<<10));    //  32 KB [8192]
  unsigned short* wx_t = (unsigned short*)(W + (64u<<20));        // 256 KB (2 layers, [64][1024])
  unsigned short* wdt_t= (unsigned short*)(W + (64u<<20) + (256u<<10)); // 128 KB
  unsigned short* wh_t = (unsigned short*)(W + (65u<<20));        // 256 KB [256][512]
  unsigned short* we_t = (unsigned short*)(W + (65u<<20) + (512u<<10)); // 160 KB [256][320]
  unsigned short* wp_t = (unsigned short*)(W + (66u<<20));        // 384 KB [512][384]

  unsigned short* v_b   = xs_b;  // [8192][320] bf16, frontend only
  unsigned short* cat_b = zs_b;  // [8192][384] bf16, frontend only

  // all weight preps + frontend conv in ONE launch
  k_wt_all<<<4816,256,0,stream>>>(in_proj_w, out_proj_w, x_proj_w, dt_proj_w,
                                  enc_w, proj_w, act_w, comm_w, val_w,
                                  obs, comm_in, conv_w, conv_b,
                                  wi_t, wo_t, wx_t, wdt_t, we_t, wp_t, wh_t,
                                  v_b, cat_b);

  // frontend GEMMs
  k_gemm_enc<<<dim3(64,4),256,0,stream>>>(v_b, we_t, enc_b, cat_b);
  k_gemm_proj<<<dim3(64,8),256,0,stream>>>(cat_b, wp_t, proj_b, h);

  for (int L=0; L<2; L++) {
    k_rms<<<2048,256,0,stream>>>(h, norm_w + L*512, u_b);
    k_gemm_inproj<<<dim3(64,16),256,0,stream>>>(u_b, wi_t + (size_t)L*2048*512,
                                                conv1d_w + L*1024*4, conv1d_b + L*1024, xs_b, zs_b);
    k_xdbl2<<<256,256,0,stream>>>(xs_b, wx_t + (size_t)L*64*1024, dt_in, bc_g);
    k_dtgate2<<<dim3(64,8),256,0,stream>>>(xs_b, zs_b, dt_in, bc_g, wdt_t + (size_t)L*1024*32,
                                           dt_proj_b + L*1024, D_param + L*1024);
    k_gemm_outproj<<<dim3(64,8),256,0,stream>>>(xs_b, wo_t + (size_t)L*512*1024, h);
  }
  k_rms<<<2048,256,0,stream>>>(h, final_nw, u_b);
  k_gemm_heads<<<dim3(64,4),256,0,stream>>>(u_b, wh_t, act_b, comm_b, val_b, out);
}